// Round 1
// baseline (1629.370 us; speedup 1.0000x reference)
//
#include <hip/hip_runtime.h>
#include <hip/hip_bf16.h>

#define NNODES 100000
#define NEDGES 800000
#define DIN    256
#define DH     128
#define KCLS   16

static constexpr float CZ = 0.95f;   // 1 - gamma*l1 + gamma*l2
static constexpr float CS = 0.10f;   // gamma*l1
static constexpr float CT = 0.05f;   // gamma*l2

__global__ __launch_bounds__(256) void init_deg_kernel(float* deg) {
    int i = blockIdx.x * 256 + threadIdx.x;
    if (i < NNODES) deg[i] = 1.0f;               // self loop
}

__global__ __launch_bounds__(256) void acc_deg_kernel(const int* __restrict__ col, float* deg) {
    int i = blockIdx.x * 256 + threadIdx.x;
    if (i < NEDGES) atomicAdd(&deg[col[i]], 1.0f);
}

__global__ __launch_bounds__(256) void dinv_kernel(float* deg) {
    int i = blockIdx.x * 256 + threadIdx.x;
    if (i < NNODES) deg[i] = 1.0f / sqrtf(deg[i]);
}

// Out[N x 128] = X[N x KD] @ W[KD x 128]
// EPI=1: W is G (128x128); fused epilogue Out = relu(CZ*X + CS*S - CT*(X@G) + bias)
template<int KD, int EPI>
__global__ __launch_bounds__(256)
void mm128_kernel(const float* __restrict__ X, const float* __restrict__ W,
                  float* __restrict__ Out, const float* __restrict__ S,
                  const float* __restrict__ bias, int nrows)
{
    __shared__ float xs[16][64];    // transposed: xs[k][r]
    __shared__ float ws[16][128];   // ws[k][c]
    const int t  = threadIdx.x;
    const int tx = t & 31;          // cols 4*tx .. 4*tx+3
    const int ty = t >> 5;          // rows 8*ty .. 8*ty+7
    const int row0 = blockIdx.x * 64;
    constexpr int LD4 = KD / 4;

    const float4* X4 = (const float4*)X;
    const float4* W4 = (const float4*)W;

    float acc[8][4] = {};

    for (int k0 = 0; k0 < KD; k0 += 16) {
        {   // stage X tile (64 rows x 16 k) transposed
            int r  = t >> 2;
            int kc = t & 3;
            int gr = row0 + r;
            float4 v = make_float4(0.f, 0.f, 0.f, 0.f);
            if (gr < nrows) v = X4[(size_t)gr * LD4 + (k0 >> 2) + kc];
            xs[kc*4+0][r] = v.x;
            xs[kc*4+1][r] = v.y;
            xs[kc*4+2][r] = v.z;
            xs[kc*4+3][r] = v.w;
        }
        {   // stage W tile (16 k x 128 c)
            float4* ws4 = (float4*)ws;
            #pragma unroll
            for (int i = 0; i < 2; ++i) {
                int idx = t + i * 256;          // 512 float4s
                int kk = idx >> 5;
                int c4 = idx & 31;
                ws4[kk*32 + c4] = W4[(size_t)(k0 + kk) * 32 + c4];
            }
        }
        __syncthreads();
        #pragma unroll
        for (int kk = 0; kk < 16; ++kk) {
            float4 a0 = *(const float4*)&xs[kk][ty*8];
            float4 a1 = *(const float4*)&xs[kk][ty*8+4];
            float4 bv = *(const float4*)&ws[kk][tx*4];
            float a[8] = {a0.x,a0.y,a0.z,a0.w,a1.x,a1.y,a1.z,a1.w};
            float b[4] = {bv.x,bv.y,bv.z,bv.w};
            #pragma unroll
            for (int i = 0; i < 8; ++i)
                #pragma unroll
                for (int j = 0; j < 4; ++j)
                    acc[i][j] = fmaf(a[i], b[j], acc[i][j]);
        }
        __syncthreads();
    }

    float4* Out4 = (float4*)Out;
    float4 bb = make_float4(0.f, 0.f, 0.f, 0.f);
    if (EPI) bb = ((const float4*)bias)[tx];
    #pragma unroll
    for (int i = 0; i < 8; ++i) {
        int gr = row0 + ty*8 + i;
        if (gr >= nrows) break;
        float4 v;
        if (EPI) {
            float4 h = X4[(size_t)gr * LD4 + tx];
            float4 s = ((const float4*)S)[(size_t)gr * 32 + tx];
            v.x = fmaxf(CZ*h.x + CS*s.x - CT*acc[i][0] + bb.x, 0.f);
            v.y = fmaxf(CZ*h.y + CS*s.y - CT*acc[i][1] + bb.y, 0.f);
            v.z = fmaxf(CZ*h.z + CS*s.z - CT*acc[i][2] + bb.z, 0.f);
            v.w = fmaxf(CZ*h.w + CS*s.w - CT*acc[i][3] + bb.w, 0.f);
        } else {
            v = make_float4(acc[i][0], acc[i][1], acc[i][2], acc[i][3]);
        }
        Out4[(size_t)gr * 32 + tx] = v;
    }
}

// G[128x128] += H^T H  (block-partial accumulators + atomics; G must be zeroed)
__global__ __launch_bounds__(256)
void gram_kernel(const float* __restrict__ H, float* __restrict__ G, int nrows)
{
    __shared__ float hs[2][128];
    const int t  = threadIdx.x;
    const int jy = t >> 4;   // G rows jy*8..+7
    const int kx = t & 15;   // G cols kx*8..+7
    float acc[8][8] = {};
    for (int r0 = blockIdx.x * 2; r0 < nrows; r0 += gridDim.x * 2) {
        {
            int rr = t >> 7, c = t & 127;
            int gr = r0 + rr;
            hs[rr][c] = (gr < nrows) ? H[(size_t)gr * DH + c] : 0.f;
        }
        __syncthreads();
        #pragma unroll
        for (int rr = 0; rr < 2; ++rr) {
            float4 a0 = *(const float4*)&hs[rr][jy*8];
            float4 a1 = *(const float4*)&hs[rr][jy*8+4];
            float4 b0 = *(const float4*)&hs[rr][kx*8];
            float4 b1 = *(const float4*)&hs[rr][kx*8+4];
            float a[8] = {a0.x,a0.y,a0.z,a0.w,a1.x,a1.y,a1.z,a1.w};
            float b[8] = {b0.x,b0.y,b0.z,b0.w,b1.x,b1.y,b1.z,b1.w};
            #pragma unroll
            for (int i = 0; i < 8; ++i)
                #pragma unroll
                for (int j = 0; j < 8; ++j)
                    acc[i][j] = fmaf(a[i], b[j], acc[i][j]);
        }
        __syncthreads();
    }
    #pragma unroll
    for (int i = 0; i < 8; ++i)
        #pragma unroll
        for (int j = 0; j < 8; ++j)
            atomicAdd(&G[(jy*8+i)*DH + kx*8+j], acc[i][j]);
}

// S[n] = dinv[n]^2 * H[n]   (self-loop init, float4 over N*32)
__global__ __launch_bounds__(256)
void sinit_kernel(const float* __restrict__ H, const float* __restrict__ dinv,
                  float* __restrict__ S)
{
    int i = blockIdx.x * 256 + threadIdx.x;
    if (i < NNODES * 32) {
        int node = i >> 5;
        float d = dinv[node];
        float d2 = d * d;
        float4 h = ((const float4*)H)[i];
        ((float4*)S)[i] = make_float4(d2*h.x, d2*h.y, d2*h.z, d2*h.w);
    }
}

// one wave per edge: S[col] += dinv[row]*dinv[col] * H[row]
__global__ __launch_bounds__(256)
void scatter_kernel(const int* __restrict__ row, const int* __restrict__ col,
                    const float* __restrict__ dinv,
                    const float* __restrict__ H, float* __restrict__ S)
{
    int wid  = (blockIdx.x * 256 + threadIdx.x) >> 6;
    int lane = threadIdx.x & 63;
    if (wid >= NEDGES) return;
    int r = row[wid], c = col[wid];
    float w = dinv[r] * dinv[c];
    const float* hrow = H + (size_t)r * DH;
    float*       srow = S + (size_t)c * DH;
    atomicAdd(&srow[lane],    w * hrow[lane]);
    atomicAdd(&srow[lane+64], w * hrow[lane+64]);
}

// out[n] = log_softmax(X[n] @ Wf + bf); one wave per node
__global__ __launch_bounds__(256)
void fc_lsm_kernel(const float* __restrict__ X, const float* __restrict__ Wf,
                   const float* __restrict__ bf, float* __restrict__ out, int nrows)
{
    __shared__ float xs[4][DH];
    const int w    = threadIdx.x >> 6;
    const int lane = threadIdx.x & 63;
    const int n    = blockIdx.x * 4 + w;
    if (n < nrows) {
        xs[w][lane]      = X[(size_t)n * DH + lane];
        xs[w][lane + 64] = X[(size_t)n * DH + lane + 64];
    }
    __syncthreads();
    if (n >= nrows || lane >= KCLS) return;
    float acc = bf[lane];
    #pragma unroll 8
    for (int j = 0; j < DH; ++j)
        acc = fmaf(xs[w][j], Wf[j * KCLS + lane], acc);
    float m = acc;
    #pragma unroll
    for (int o = 8; o >= 1; o >>= 1)
        m = fmaxf(m, __shfl_xor(m, o, 16));
    float e = expf(acc - m);
    float ssum = e;
    #pragma unroll
    for (int o = 8; o >= 1; o >>= 1)
        ssum += __shfl_xor(ssum, o, 16);
    out[(size_t)n * KCLS + lane] = acc - m - logf(ssum);
}

extern "C" void kernel_launch(void* const* d_in, const int* in_sizes, int n_in,
                              void* d_out, int out_size, void* d_ws, size_t ws_size,
                              hipStream_t stream) {
    const float* x  = (const float*)d_in[0];
    const int*   ei = (const int*)d_in[1];
    const float* W1 = (const float*)d_in[2];
    const float* b1 = (const float*)d_in[3];
    const float* W2 = (const float*)d_in[4];
    const float* b2 = (const float*)d_in[5];
    const float* Wf = (const float*)d_in[6];
    const float* bf = (const float*)d_in[7];
    float* out = (float*)d_out;

    const int* row = ei;            // edge_index[0] = source
    const int* col = ei + NEDGES;   // edge_index[1] = target

    float* ws   = (float*)d_ws;
    float* dinv = ws;                                   // N (padded to 102400)
    float* B0   = ws + 102400;                          // N*128
    float* B1   = B0 + (size_t)NNODES * DH;             // N*128
    float* G    = B1 + (size_t)NNODES * DH;             // 128*128

    dim3 b256(256);
    const int gN   = (NNODES + 255) / 256;
    const int gE   = (NEDGES + 255) / 256;
    const int gMM  = (NNODES + 63) / 64;
    const int gSI  = (NNODES * 32 + 255) / 256;
    const int gSC  = NEDGES / 4;        // 4 waves/block, 1 wave per edge

    // degrees -> dinv
    init_deg_kernel<<<gN, b256, 0, stream>>>(dinv);
    acc_deg_kernel<<<gE, b256, 0, stream>>>(col, dinv);
    dinv_kernel<<<gN, b256, 0, stream>>>(dinv);

    // ---- layer 1 ----
    mm128_kernel<DIN, 0><<<gMM, b256, 0, stream>>>(x, W1, B0, nullptr, nullptr, NNODES);
    hipMemsetAsync(G, 0, DH * DH * sizeof(float), stream);
    gram_kernel<<<256, b256, 0, stream>>>(B0, G, NNODES);
    sinit_kernel<<<gSI, b256, 0, stream>>>(B0, dinv, B1);
    scatter_kernel<<<gSC, b256, 0, stream>>>(row, col, dinv, B0, B1);
    mm128_kernel<DH, 1><<<gMM, b256, 0, stream>>>(B0, G, B1, B1, b1, NNODES);

    // ---- layer 2 ----
    mm128_kernel<DH, 0><<<gMM, b256, 0, stream>>>(B1, W2, B0, nullptr, nullptr, NNODES);
    hipMemsetAsync(G, 0, DH * DH * sizeof(float), stream);
    gram_kernel<<<256, b256, 0, stream>>>(B0, G, NNODES);
    sinit_kernel<<<gSI, b256, 0, stream>>>(B0, dinv, B1);
    scatter_kernel<<<gSC, b256, 0, stream>>>(row, col, dinv, B0, B1);
    mm128_kernel<DH, 1><<<gMM, b256, 0, stream>>>(B0, G, B1, B1, b2, NNODES);

    // ---- fc + log_softmax ----
    fc_lsm_kernel<<<(NNODES + 3) / 4, b256, 0, stream>>>(B1, Wf, bf, out, NNODES);
}

// Round 2
// 1179.136 us; speedup vs baseline: 1.3818x; 1.3818x over previous
//
#include <hip/hip_runtime.h>
#include <hip/hip_bf16.h>

#define NNODES 100000
#define NEDGES 800000
#define DIN    256
#define DH     128
#define KCLS   16
#define SCAN_NBLK 98   // ceil(100000/1024)

static constexpr float CZ = 0.95f;   // 1 - gamma*l1 + gamma*l2
static constexpr float CS = 0.10f;   // gamma*l1
static constexpr float CT = 0.05f;   // gamma*l2

// ---------------- degree / CSR build ----------------

__global__ __launch_bounds__(256) void hist_kernel(const int* __restrict__ col, int* counts) {
    int i = blockIdx.x * 256 + threadIdx.x;
    if (i < NEDGES) atomicAdd(&counts[col[i]], 1);
}

__global__ __launch_bounds__(256) void dinv_kernel(const int* __restrict__ counts, float* dinv) {
    int i = blockIdx.x * 256 + threadIdx.x;
    if (i < NNODES) dinv[i] = rsqrtf((float)(counts[i] + 1));   // +1 self loop
}

// exclusive scan of counts[N] -> offsets[N]; per-block (1024 elems) + bsum
__global__ __launch_bounds__(256) void scan1_kernel(const int* __restrict__ counts,
                                                    int* __restrict__ offsets, int* __restrict__ bsum) {
    __shared__ int ls[256];
    const int b = blockIdx.x, t = threadIdx.x;
    const int base = b * 1024 + t * 4;
    int v0 = (base + 0 < NNODES) ? counts[base + 0] : 0;
    int v1 = (base + 1 < NNODES) ? counts[base + 1] : 0;
    int v2 = (base + 2 < NNODES) ? counts[base + 2] : 0;
    int v3 = (base + 3 < NNODES) ? counts[base + 3] : 0;
    ls[t] = v0 + v1 + v2 + v3;
    __syncthreads();
    for (int off = 1; off < 256; off <<= 1) {
        int v = (t >= off) ? ls[t - off] : 0;
        __syncthreads();
        ls[t] += v;
        __syncthreads();
    }
    int excl = (t == 0) ? 0 : ls[t - 1];
    if (t == 255) bsum[b] = ls[255];
    if (base + 0 < NNODES) offsets[base + 0] = excl;
    if (base + 1 < NNODES) offsets[base + 1] = excl + v0;
    if (base + 2 < NNODES) offsets[base + 2] = excl + v0 + v1;
    if (base + 3 < NNODES) offsets[base + 3] = excl + v0 + v1 + v2;
}

__global__ void scan2_kernel(int* bsum) {
    if (threadIdx.x == 0 && blockIdx.x == 0) {
        int s = 0;
        for (int b = 0; b < SCAN_NBLK; ++b) { int v = bsum[b]; bsum[b] = s; s += v; }
    }
}

__global__ __launch_bounds__(256) void scan3_kernel(int* __restrict__ offsets, const int* __restrict__ bsum) {
    const int b = blockIdx.x, t = threadIdx.x;
    const int add = bsum[b];
    const int base = b * 1024 + t * 4;
    #pragma unroll
    for (int i = 0; i < 4; ++i)
        if (base + i < NNODES) offsets[base + i] += add;
    if (b == 0 && t == 0) offsets[NNODES] = NEDGES;
}

__global__ __launch_bounds__(256)
void fill_kernel(const int* __restrict__ row, const int* __restrict__ col,
                 const float* __restrict__ dinv, const int* __restrict__ offsets,
                 int* __restrict__ cursor, int* __restrict__ eidx, float* __restrict__ ew) {
    int e = blockIdx.x * 256 + threadIdx.x;
    if (e >= NEDGES) return;
    int c = col[e], r = row[e];
    int p = offsets[c] + atomicAdd(&cursor[c], 1);
    eidx[p] = r;
    ew[p] = dinv[r] * dinv[c];
}

// S[c] = dinv[c]^2 * H[c] + sum_{e->c} w_e * H[row_e]; one wave per node
__global__ __launch_bounds__(256)
void gather_kernel(const float* __restrict__ H, const float* __restrict__ dinv,
                   const int* __restrict__ offsets, const int* __restrict__ eidx,
                   const float* __restrict__ ew, float* __restrict__ S) {
    const int wid  = (blockIdx.x * 256 + threadIdx.x) >> 6;
    const int lane = threadIdx.x & 63;
    if (wid >= NNODES) return;
    const float2* H2 = (const float2*)H;
    float d = dinv[wid];
    float2 h = H2[(size_t)wid * 64 + lane];
    float ax = d * d * h.x, ay = d * d * h.y;
    const int s = offsets[wid], e = offsets[wid + 1];
    for (int p = s; p < e; ++p) {
        int r = eidx[p];
        float w = ew[p];
        float2 hh = H2[(size_t)r * 64 + lane];
        ax = fmaf(w, hh.x, ax);
        ay = fmaf(w, hh.y, ay);
    }
    ((float2*)S)[(size_t)wid * 64 + lane] = make_float2(ax, ay);
}

// ---------------- dense kernels (unchanged from round 1) ----------------

// Out[N x 128] = X[N x KD] @ W[KD x 128]
// EPI=1: W is G (128x128); fused epilogue Out = relu(CZ*X + CS*S - CT*(X@G) + bias)
template<int KD, int EPI>
__global__ __launch_bounds__(256)
void mm128_kernel(const float* __restrict__ X, const float* __restrict__ W,
                  float* __restrict__ Out, const float* __restrict__ S,
                  const float* __restrict__ bias, int nrows)
{
    __shared__ float xs[16][64];    // transposed: xs[k][r]
    __shared__ float ws[16][128];   // ws[k][c]
    const int t  = threadIdx.x;
    const int tx = t & 31;          // cols 4*tx .. 4*tx+3
    const int ty = t >> 5;          // rows 8*ty .. 8*ty+7
    const int row0 = blockIdx.x * 64;
    constexpr int LD4 = KD / 4;

    const float4* X4 = (const float4*)X;
    const float4* W4 = (const float4*)W;

    float acc[8][4] = {};

    for (int k0 = 0; k0 < KD; k0 += 16) {
        {   // stage X tile (64 rows x 16 k) transposed
            int r  = t >> 2;
            int kc = t & 3;
            int gr = row0 + r;
            float4 v = make_float4(0.f, 0.f, 0.f, 0.f);
            if (gr < nrows) v = X4[(size_t)gr * LD4 + (k0 >> 2) + kc];
            xs[kc*4+0][r] = v.x;
            xs[kc*4+1][r] = v.y;
            xs[kc*4+2][r] = v.z;
            xs[kc*4+3][r] = v.w;
        }
        {   // stage W tile (16 k x 128 c)
            float4* ws4 = (float4*)ws;
            #pragma unroll
            for (int i = 0; i < 2; ++i) {
                int idx = t + i * 256;          // 512 float4s
                int kk = idx >> 5;
                int c4 = idx & 31;
                ws4[kk*32 + c4] = W4[(size_t)(k0 + kk) * 32 + c4];
            }
        }
        __syncthreads();
        #pragma unroll
        for (int kk = 0; kk < 16; ++kk) {
            float4 a0 = *(const float4*)&xs[kk][ty*8];
            float4 a1 = *(const float4*)&xs[kk][ty*8+4];
            float4 bv = *(const float4*)&ws[kk][tx*4];
            float a[8] = {a0.x,a0.y,a0.z,a0.w,a1.x,a1.y,a1.z,a1.w};
            float b[4] = {bv.x,bv.y,bv.z,bv.w};
            #pragma unroll
            for (int i = 0; i < 8; ++i)
                #pragma unroll
                for (int j = 0; j < 4; ++j)
                    acc[i][j] = fmaf(a[i], b[j], acc[i][j]);
        }
        __syncthreads();
    }

    float4* Out4 = (float4*)Out;
    float4 bb = make_float4(0.f, 0.f, 0.f, 0.f);
    if (EPI) bb = ((const float4*)bias)[tx];
    #pragma unroll
    for (int i = 0; i < 8; ++i) {
        int gr = row0 + ty*8 + i;
        if (gr >= nrows) break;
        float4 v;
        if (EPI) {
            float4 h = X4[(size_t)gr * LD4 + tx];
            float4 s = ((const float4*)S)[(size_t)gr * 32 + tx];
            v.x = fmaxf(CZ*h.x + CS*s.x - CT*acc[i][0] + bb.x, 0.f);
            v.y = fmaxf(CZ*h.y + CS*s.y - CT*acc[i][1] + bb.y, 0.f);
            v.z = fmaxf(CZ*h.z + CS*s.z - CT*acc[i][2] + bb.z, 0.f);
            v.w = fmaxf(CZ*h.w + CS*s.w - CT*acc[i][3] + bb.w, 0.f);
        } else {
            v = make_float4(acc[i][0], acc[i][1], acc[i][2], acc[i][3]);
        }
        Out4[(size_t)gr * 32 + tx] = v;
    }
}

// G[128x128] += H^T H  (block-partial accumulators + atomics; G must be zeroed)
__global__ __launch_bounds__(256)
void gram_kernel(const float* __restrict__ H, float* __restrict__ G, int nrows)
{
    __shared__ float hs[2][128];
    const int t  = threadIdx.x;
    const int jy = t >> 4;   // G rows jy*8..+7
    const int kx = t & 15;   // G cols kx*8..+7
    float acc[8][8] = {};
    for (int r0 = blockIdx.x * 2; r0 < nrows; r0 += gridDim.x * 2) {
        {
            int rr = t >> 7, c = t & 127;
            int gr = r0 + rr;
            hs[rr][c] = (gr < nrows) ? H[(size_t)gr * DH + c] : 0.f;
        }
        __syncthreads();
        #pragma unroll
        for (int rr = 0; rr < 2; ++rr) {
            float4 a0 = *(const float4*)&hs[rr][jy*8];
            float4 a1 = *(const float4*)&hs[rr][jy*8+4];
            float4 b0 = *(const float4*)&hs[rr][kx*8];
            float4 b1 = *(const float4*)&hs[rr][kx*8+4];
            float a[8] = {a0.x,a0.y,a0.z,a0.w,a1.x,a1.y,a1.z,a1.w};
            float b[8] = {b0.x,b0.y,b0.z,b0.w,b1.x,b1.y,b1.z,b1.w};
            #pragma unroll
            for (int i = 0; i < 8; ++i)
                #pragma unroll
                for (int j = 0; j < 8; ++j)
                    acc[i][j] = fmaf(a[i], b[j], acc[i][j]);
        }
        __syncthreads();
    }
    #pragma unroll
    for (int i = 0; i < 8; ++i)
        #pragma unroll
        for (int j = 0; j < 8; ++j)
            atomicAdd(&G[(jy*8+i)*DH + kx*8+j], acc[i][j]);
}

// out[n] = log_softmax(X[n] @ Wf + bf); one wave per node
__global__ __launch_bounds__(256)
void fc_lsm_kernel(const float* __restrict__ X, const float* __restrict__ Wf,
                   const float* __restrict__ bf, float* __restrict__ out, int nrows)
{
    __shared__ float xs[4][DH];
    const int w    = threadIdx.x >> 6;
    const int lane = threadIdx.x & 63;
    const int n    = blockIdx.x * 4 + w;
    if (n < nrows) {
        xs[w][lane]      = X[(size_t)n * DH + lane];
        xs[w][lane + 64] = X[(size_t)n * DH + lane + 64];
    }
    __syncthreads();
    if (n >= nrows || lane >= KCLS) return;
    float acc = bf[lane];
    #pragma unroll 8
    for (int j = 0; j < DH; ++j)
        acc = fmaf(xs[w][j], Wf[j * KCLS + lane], acc);
    float m = acc;
    #pragma unroll
    for (int o = 8; o >= 1; o >>= 1)
        m = fmaxf(m, __shfl_xor(m, o, 16));
    float e = expf(acc - m);
    float ssum = e;
    #pragma unroll
    for (int o = 8; o >= 1; o >>= 1)
        ssum += __shfl_xor(ssum, o, 16);
    out[(size_t)n * KCLS + lane] = acc - m - logf(ssum);
}

extern "C" void kernel_launch(void* const* d_in, const int* in_sizes, int n_in,
                              void* d_out, int out_size, void* d_ws, size_t ws_size,
                              hipStream_t stream) {
    const float* x  = (const float*)d_in[0];
    const int*   ei = (const int*)d_in[1];
    const float* W1 = (const float*)d_in[2];
    const float* b1 = (const float*)d_in[3];
    const float* W2 = (const float*)d_in[4];
    const float* b2 = (const float*)d_in[5];
    const float* Wf = (const float*)d_in[6];
    const float* bf = (const float*)d_in[7];
    float* out = (float*)d_out;

    const int* row = ei;            // edge_index[0] = source
    const int* col = ei + NEDGES;   // edge_index[1] = target

    float* ws   = (float*)d_ws;
    float* dinv = ws;                                   // 102400
    float* B0   = ws + 102400;                          // N*128
    float* B1   = B0 + (size_t)NNODES * DH;             // N*128
    float* G    = B1 + (size_t)NNODES * DH;             // 128*128
    int*   counts  = (int*)(G + DH * DH);               // 102400 (also cursor)
    int*   offsets = counts + 102400;                   // N+1 (padded 102656)
    int*   bsum    = offsets + 102656;                  // 128
    int*   eidx    = bsum + 128;                        // E
    float* ew      = (float*)(eidx + NEDGES);           // E

    dim3 b256(256);
    const int gN   = (NNODES + 255) / 256;
    const int gE   = (NEDGES + 255) / 256;
    const int gMM  = (NNODES + 63) / 64;
    const int gGA  = (NNODES * 64 + 255) / 256;   // 1 wave/node

    // ---- degrees + CSR build ----
    hipMemsetAsync(counts, 0, NNODES * sizeof(int), stream);
    hist_kernel<<<gE, b256, 0, stream>>>(col, counts);
    dinv_kernel<<<gN, b256, 0, stream>>>(counts, dinv);
    scan1_kernel<<<SCAN_NBLK, b256, 0, stream>>>(counts, offsets, bsum);
    scan2_kernel<<<1, 64, 0, stream>>>(bsum);
    scan3_kernel<<<SCAN_NBLK, b256, 0, stream>>>(offsets, bsum);
    hipMemsetAsync(counts, 0, NNODES * sizeof(int), stream);   // reuse as cursor
    fill_kernel<<<gE, b256, 0, stream>>>(row, col, dinv, offsets, counts, eidx, ew);

    // ---- layer 1 ----
    mm128_kernel<DIN, 0><<<gMM, b256, 0, stream>>>(x, W1, B0, nullptr, nullptr, NNODES);
    hipMemsetAsync(G, 0, DH * DH * sizeof(float), stream);
    gram_kernel<<<256, b256, 0, stream>>>(B0, G, NNODES);
    gather_kernel<<<gGA, b256, 0, stream>>>(B0, dinv, offsets, eidx, ew, B1);
    mm128_kernel<DH, 1><<<gMM, b256, 0, stream>>>(B0, G, B1, B1, b1, NNODES);

    // ---- layer 2 ----
    mm128_kernel<DH, 0><<<gMM, b256, 0, stream>>>(B1, W2, B0, nullptr, nullptr, NNODES);
    hipMemsetAsync(G, 0, DH * DH * sizeof(float), stream);
    gram_kernel<<<256, b256, 0, stream>>>(B0, G, NNODES);
    gather_kernel<<<gGA, b256, 0, stream>>>(B0, dinv, offsets, eidx, ew, B1);
    mm128_kernel<DH, 1><<<gMM, b256, 0, stream>>>(B0, G, B1, B1, b2, NNODES);

    // ---- fc + log_softmax ----
    fc_lsm_kernel<<<(NNODES + 3) / 4, b256, 0, stream>>>(B1, Wf, bf, out, NNODES);
}

// Round 3
// 1004.294 us; speedup vs baseline: 1.6224x; 1.1741x over previous
//
#include <hip/hip_runtime.h>
#include <hip/hip_bf16.h>

#define NNODES 100000
#define NEDGES 800000
#define DIN    256
#define DH     128
#define KCLS   16
#define SCAN_NBLK 98   // ceil(100000/1024)
#define GR 16          // gram rows per tile

static constexpr float CZ = 0.95f;   // 1 - gamma*l1 + gamma*l2
static constexpr float CS = 0.10f;   // gamma*l1
static constexpr float CT = 0.05f;   // gamma*l2

// ---------------- degree / CSR build ----------------

__global__ __launch_bounds__(256) void hist_kernel(const int* __restrict__ col, int* counts) {
    int i = blockIdx.x * 256 + threadIdx.x;
    if (i < NEDGES) atomicAdd(&counts[col[i]], 1);
}

__global__ __launch_bounds__(256) void dinv_kernel(const int* __restrict__ counts, float* dinv) {
    int i = blockIdx.x * 256 + threadIdx.x;
    if (i < NNODES) dinv[i] = rsqrtf((float)(counts[i] + 1));   // +1 self loop
}

// exclusive scan of counts[N] -> offsets[N]; per-block (1024 elems) + bsum
__global__ __launch_bounds__(256) void scan1_kernel(const int* __restrict__ counts,
                                                    int* __restrict__ offsets, int* __restrict__ bsum) {
    __shared__ int ls[256];
    const int b = blockIdx.x, t = threadIdx.x;
    const int base = b * 1024 + t * 4;
    int v0 = (base + 0 < NNODES) ? counts[base + 0] : 0;
    int v1 = (base + 1 < NNODES) ? counts[base + 1] : 0;
    int v2 = (base + 2 < NNODES) ? counts[base + 2] : 0;
    int v3 = (base + 3 < NNODES) ? counts[base + 3] : 0;
    ls[t] = v0 + v1 + v2 + v3;
    __syncthreads();
    for (int off = 1; off < 256; off <<= 1) {
        int v = (t >= off) ? ls[t - off] : 0;
        __syncthreads();
        ls[t] += v;
        __syncthreads();
    }
    int excl = (t == 0) ? 0 : ls[t - 1];
    if (t == 255) bsum[b] = ls[255];
    if (base + 0 < NNODES) offsets[base + 0] = excl;
    if (base + 1 < NNODES) offsets[base + 1] = excl + v0;
    if (base + 2 < NNODES) offsets[base + 2] = excl + v0 + v1;
    if (base + 3 < NNODES) offsets[base + 3] = excl + v0 + v1 + v2;
}

__global__ void scan2_kernel(int* bsum) {
    if (threadIdx.x == 0 && blockIdx.x == 0) {
        int s = 0;
        for (int b = 0; b < SCAN_NBLK; ++b) { int v = bsum[b]; bsum[b] = s; s += v; }
    }
}

__global__ __launch_bounds__(256) void scan3_kernel(int* __restrict__ offsets, const int* __restrict__ bsum) {
    const int b = blockIdx.x, t = threadIdx.x;
    const int add = bsum[b];
    const int base = b * 1024 + t * 4;
    #pragma unroll
    for (int i = 0; i < 4; ++i)
        if (base + i < NNODES) offsets[base + i] += add;
    if (b == 0 && t == 0) offsets[NNODES] = NEDGES;
}

__global__ __launch_bounds__(256)
void fill_kernel(const int* __restrict__ row, const int* __restrict__ col,
                 const float* __restrict__ dinv, const int* __restrict__ offsets,
                 int* __restrict__ cursor, int* __restrict__ eidx, float* __restrict__ ew) {
    int e = blockIdx.x * 256 + threadIdx.x;
    if (e >= NEDGES) return;
    int c = col[e], r = row[e];
    int p = offsets[c] + atomicAdd(&cursor[c], 1);
    eidx[p] = r;
    ew[p] = dinv[r] * dinv[c];
}

// S[c] = dinv[c]^2 * H[c] + sum_{e->c} w_e * H[row_e]; one wave per node
__global__ __launch_bounds__(256)
void gather_kernel(const float* __restrict__ H, const float* __restrict__ dinv,
                   const int* __restrict__ offsets, const int* __restrict__ eidx,
                   const float* __restrict__ ew, float* __restrict__ S) {
    const int wid  = (blockIdx.x * 256 + threadIdx.x) >> 6;
    const int lane = threadIdx.x & 63;
    if (wid >= NNODES) return;
    const float2* H2 = (const float2*)H;
    float d = dinv[wid];
    float2 h = H2[(size_t)wid * 64 + lane];
    float ax = d * d * h.x, ay = d * d * h.y;
    const int s = offsets[wid], e = offsets[wid + 1];
    for (int p = s; p < e; ++p) {
        int r = eidx[p];
        float w = ew[p];
        float2 hh = H2[(size_t)r * 64 + lane];
        ax = fmaf(w, hh.x, ax);
        ay = fmaf(w, hh.y, ay);
    }
    ((float2*)S)[(size_t)wid * 64 + lane] = make_float2(ax, ay);
}

// ---------------- dense kernels ----------------

// Out[N x 128] = X[N x KD] @ W[KD x 128]
// EPI=1: W is G (128x128); fused epilogue Out = relu(CZ*X + CS*S - CT*(X@G) + bias)
template<int KD, int EPI>
__global__ __launch_bounds__(256)
void mm128_kernel(const float* __restrict__ X, const float* __restrict__ W,
                  float* __restrict__ Out, const float* __restrict__ S,
                  const float* __restrict__ bias, int nrows)
{
    __shared__ float xs[16][64];    // transposed: xs[k][r]
    __shared__ float ws[16][128];   // ws[k][c]
    const int t  = threadIdx.x;
    const int tx = t & 31;          // cols 4*tx .. 4*tx+3
    const int ty = t >> 5;          // rows 8*ty .. 8*ty+7
    const int row0 = blockIdx.x * 64;
    constexpr int LD4 = KD / 4;

    const float4* X4 = (const float4*)X;
    const float4* W4 = (const float4*)W;

    float acc[8][4] = {};

    for (int k0 = 0; k0 < KD; k0 += 16) {
        {   // stage X tile (64 rows x 16 k) transposed
            int r  = t >> 2;
            int kc = t & 3;
            int gr = row0 + r;
            float4 v = make_float4(0.f, 0.f, 0.f, 0.f);
            if (gr < nrows) v = X4[(size_t)gr * LD4 + (k0 >> 2) + kc];
            xs[kc*4+0][r] = v.x;
            xs[kc*4+1][r] = v.y;
            xs[kc*4+2][r] = v.z;
            xs[kc*4+3][r] = v.w;
        }
        {   // stage W tile (16 k x 128 c)
            float4* ws4 = (float4*)ws;
            #pragma unroll
            for (int i = 0; i < 2; ++i) {
                int idx = t + i * 256;          // 512 float4s
                int kk = idx >> 5;
                int c4 = idx & 31;
                ws4[kk*32 + c4] = W4[(size_t)(k0 + kk) * 32 + c4];
            }
        }
        __syncthreads();
        #pragma unroll
        for (int kk = 0; kk < 16; ++kk) {
            float4 a0 = *(const float4*)&xs[kk][ty*8];
            float4 a1 = *(const float4*)&xs[kk][ty*8+4];
            float4 bv = *(const float4*)&ws[kk][tx*4];
            float a[8] = {a0.x,a0.y,a0.z,a0.w,a1.x,a1.y,a1.z,a1.w};
            float b[4] = {bv.x,bv.y,bv.z,bv.w};
            #pragma unroll
            for (int i = 0; i < 8; ++i)
                #pragma unroll
                for (int j = 0; j < 4; ++j)
                    acc[i][j] = fmaf(a[i], b[j], acc[i][j]);
        }
        __syncthreads();
    }

    float4* Out4 = (float4*)Out;
    float4 bb = make_float4(0.f, 0.f, 0.f, 0.f);
    if (EPI) bb = ((const float4*)bias)[tx];
    #pragma unroll
    for (int i = 0; i < 8; ++i) {
        int gr = row0 + ty*8 + i;
        if (gr >= nrows) break;
        float4 v;
        if (EPI) {
            float4 h = X4[(size_t)gr * LD4 + tx];
            float4 s = ((const float4*)S)[(size_t)gr * 32 + tx];
            v.x = fmaxf(CZ*h.x + CS*s.x - CT*acc[i][0] + bb.x, 0.f);
            v.y = fmaxf(CZ*h.y + CS*s.y - CT*acc[i][1] + bb.y, 0.f);
            v.z = fmaxf(CZ*h.z + CS*s.z - CT*acc[i][2] + bb.z, 0.f);
            v.w = fmaxf(CZ*h.w + CS*s.w - CT*acc[i][3] + bb.w, 0.f);
        } else {
            v = make_float4(acc[i][0], acc[i][1], acc[i][2], acc[i][3]);
        }
        Out4[(size_t)gr * 32 + tx] = v;
    }
}

// G[128x128] += H^T H
// 16-row double-buffered tiles, async stage (loads early, ds_write late),
// split-halves fragment map (stride-4 -> 2-way LDS aliasing = free).
__global__ __launch_bounds__(256)
void gram_kernel(const float* __restrict__ H, float* __restrict__ G, int nrows)
{
    __shared__ float hs[2][GR][DH];
    const int t  = threadIdx.x;
    const int jy = t >> 4;   // a-rows: jy*4..+3 and 64+jy*4..+3
    const int kx = t & 15;   // b-cols: kx*4..+3 and 64+kx*4..+3
    const int rr0 = t >> 5, c40 = t & 31;          // staging slot 0 (idx t)
    const int rr1 = (t + 256) >> 5, c41 = c40;     // staging slot 1 (idx t+256)

    float acc[8][8] = {};
    const int step = gridDim.x * GR;
    int r0 = blockIdx.x * GR;
    const float4* H4 = (const float4*)H;

    // prologue: stage first tile into buf 0
    {
        int g0 = r0 + rr0, g1 = r0 + rr1;
        float4 v0 = make_float4(0.f,0.f,0.f,0.f), v1 = v0;
        if (g0 < nrows) v0 = H4[(size_t)g0 * 32 + c40];
        if (g1 < nrows) v1 = H4[(size_t)g1 * 32 + c41];
        *(float4*)&hs[0][rr0][c40*4] = v0;
        *(float4*)&hs[0][rr1][c41*4] = v1;
    }
    __syncthreads();

    int buf = 0;
    for (; r0 < nrows; r0 += step, buf ^= 1) {
        // issue next tile's loads early (latency hides under compute)
        int rn = r0 + step;
        float4 v0 = make_float4(0.f,0.f,0.f,0.f), v1 = v0;
        if (rn < nrows) {
            int g0 = rn + rr0, g1 = rn + rr1;
            if (g0 < nrows) v0 = H4[(size_t)g0 * 32 + c40];
            if (g1 < nrows) v1 = H4[(size_t)g1 * 32 + c41];
        }
        // compute current tile
        #pragma unroll
        for (int rr = 0; rr < GR; ++rr) {
            float4 a0 = *(const float4*)&hs[buf][rr][jy*4];
            float4 a1 = *(const float4*)&hs[buf][rr][64 + jy*4];
            float4 b0 = *(const float4*)&hs[buf][rr][kx*4];
            float4 b1 = *(const float4*)&hs[buf][rr][64 + kx*4];
            float a[8] = {a0.x,a0.y,a0.z,a0.w,a1.x,a1.y,a1.z,a1.w};
            float b[8] = {b0.x,b0.y,b0.z,b0.w,b1.x,b1.y,b1.z,b1.w};
            #pragma unroll
            for (int i = 0; i < 8; ++i)
                #pragma unroll
                for (int j = 0; j < 8; ++j)
                    acc[i][j] = fmaf(a[i], b[j], acc[i][j]);
        }
        // write next tile into other buffer
        if (rn < nrows) {
            *(float4*)&hs[buf ^ 1][rr0][c40*4] = v0;
            *(float4*)&hs[buf ^ 1][rr1][c41*4] = v1;
        }
        __syncthreads();
    }

    #pragma unroll
    for (int i = 0; i < 8; ++i) {
        int ar = (i < 4) ? (jy*4 + i) : (64 + jy*4 + i - 4);
        #pragma unroll
        for (int j = 0; j < 8; ++j) {
            int bc = (j < 4) ? (kx*4 + j) : (64 + kx*4 + j - 4);
            atomicAdd(&G[ar * DH + bc], acc[i][j]);
        }
    }
}

// out[n] = log_softmax(X[n] @ Wf + bf); one wave per node
__global__ __launch_bounds__(256)
void fc_lsm_kernel(const float* __restrict__ X, const float* __restrict__ Wf,
                   const float* __restrict__ bf, float* __restrict__ out, int nrows)
{
    __shared__ float xs[4][DH];
    const int w    = threadIdx.x >> 6;
    const int lane = threadIdx.x & 63;
    const int n    = blockIdx.x * 4 + w;
    if (n < nrows) {
        xs[w][lane]      = X[(size_t)n * DH + lane];
        xs[w][lane + 64] = X[(size_t)n * DH + lane + 64];
    }
    __syncthreads();
    if (n >= nrows || lane >= KCLS) return;
    float acc = bf[lane];
    #pragma unroll 8
    for (int j = 0; j < DH; ++j)
        acc = fmaf(xs[w][j], Wf[j * KCLS + lane], acc);
    float m = acc;
    #pragma unroll
    for (int o = 8; o >= 1; o >>= 1)
        m = fmaxf(m, __shfl_xor(m, o, 16));
    float e = expf(acc - m);
    float ssum = e;
    #pragma unroll
    for (int o = 8; o >= 1; o >>= 1)
        ssum += __shfl_xor(ssum, o, 16);
    out[(size_t)n * KCLS + lane] = acc - m - logf(ssum);
}

extern "C" void kernel_launch(void* const* d_in, const int* in_sizes, int n_in,
                              void* d_out, int out_size, void* d_ws, size_t ws_size,
                              hipStream_t stream) {
    const float* x  = (const float*)d_in[0];
    const int*   ei = (const int*)d_in[1];
    const float* W1 = (const float*)d_in[2];
    const float* b1 = (const float*)d_in[3];
    const float* W2 = (const float*)d_in[4];
    const float* b2 = (const float*)d_in[5];
    const float* Wf = (const float*)d_in[6];
    const float* bf = (const float*)d_in[7];
    float* out = (float*)d_out;

    const int* row = ei;            // edge_index[0] = source
    const int* col = ei + NEDGES;   // edge_index[1] = target

    float* ws   = (float*)d_ws;
    float* dinv = ws;                                   // 102400
    float* B0   = ws + 102400;                          // N*128
    float* B1   = B0 + (size_t)NNODES * DH;             // N*128
    float* G    = B1 + (size_t)NNODES * DH;             // 128*128
    int*   counts  = (int*)(G + DH * DH);               // 102400 (also cursor)
    int*   offsets = counts + 102400;                   // N+1 (padded 102656)
    int*   bsum    = offsets + 102656;                  // 128
    int*   eidx    = bsum + 128;                        // E
    float* ew      = (float*)(eidx + NEDGES);           // E

    dim3 b256(256);
    const int gN   = (NNODES + 255) / 256;
    const int gE   = (NEDGES + 255) / 256;
    const int gMM  = (NNODES + 63) / 64;
    const int gGA  = (NNODES * 64 + 255) / 256;   // 1 wave/node
    const int gGR  = 512;                         // gram blocks (2/CU)

    // ---- degrees + CSR build ----
    hipMemsetAsync(counts, 0, NNODES * sizeof(int), stream);
    hist_kernel<<<gE, b256, 0, stream>>>(col, counts);
    dinv_kernel<<<gN, b256, 0, stream>>>(counts, dinv);
    scan1_kernel<<<SCAN_NBLK, b256, 0, stream>>>(counts, offsets, bsum);
    scan2_kernel<<<1, 64, 0, stream>>>(bsum);
    scan3_kernel<<<SCAN_NBLK, b256, 0, stream>>>(offsets, bsum);
    hipMemsetAsync(counts, 0, NNODES * sizeof(int), stream);   // reuse as cursor
    fill_kernel<<<gE, b256, 0, stream>>>(row, col, dinv, offsets, counts, eidx, ew);

    // ---- layer 1 ----
    mm128_kernel<DIN, 0><<<gMM, b256, 0, stream>>>(x, W1, B0, nullptr, nullptr, NNODES);
    hipMemsetAsync(G, 0, DH * DH * sizeof(float), stream);
    gram_kernel<<<gGR, b256, 0, stream>>>(B0, G, NNODES);
    gather_kernel<<<gGA, b256, 0, stream>>>(B0, dinv, offsets, eidx, ew, B1);
    mm128_kernel<DH, 1><<<gMM, b256, 0, stream>>>(B0, G, B1, B1, b1, NNODES);

    // ---- layer 2 ----
    mm128_kernel<DH, 0><<<gMM, b256, 0, stream>>>(B1, W2, B0, nullptr, nullptr, NNODES);
    hipMemsetAsync(G, 0, DH * DH * sizeof(float), stream);
    gram_kernel<<<gGR, b256, 0, stream>>>(B0, G, NNODES);
    gather_kernel<<<gGA, b256, 0, stream>>>(B0, dinv, offsets, eidx, ew, B1);
    mm128_kernel<DH, 1><<<gMM, b256, 0, stream>>>(B0, G, B1, B1, b2, NNODES);

    // ---- fc + log_softmax ----
    fc_lsm_kernel<<<(NNODES + 3) / 4, b256, 0, stream>>>(B1, Wf, bf, out, NNODES);
}

// Round 4
// 538.827 us; speedup vs baseline: 3.0239x; 1.8639x over previous
//
#include <hip/hip_runtime.h>

#define NNODES 100000
#define NEDGES 800000
#define DIN    256
#define DH     128
#define KCLS   16
#define SCAN_NBLK 98   // ceil(100000/1024)
#define GCH 64         // gram K-chunk rows
#define GRAM_BLK 256   // gram partial blocks

typedef unsigned short u16;
typedef short s16x8 __attribute__((ext_vector_type(8)));
typedef float f32x4 __attribute__((ext_vector_type(4)));

static constexpr float CZ = 0.95f;   // 1 - gamma*l1 + gamma*l2
static constexpr float CS = 0.10f;   // gamma*l1
static constexpr float CT = 0.05f;   // gamma*l2

__device__ __forceinline__ u16 f2b(float f) {           // fp32 -> bf16 RNE
    unsigned u = __builtin_bit_cast(unsigned, f);
    return (u16)((u + 0x7FFFu + ((u >> 16) & 1u)) >> 16);
}
__device__ __forceinline__ float b2f(u16 b) {
    return __builtin_bit_cast(float, ((unsigned)b) << 16);
}

// ---------------- degree / CSR build ----------------

__global__ __launch_bounds__(256) void hist_kernel(const int* __restrict__ col, int* counts) {
    int i = blockIdx.x * 256 + threadIdx.x;
    if (i < NEDGES) atomicAdd(&counts[col[i]], 1);
}

__global__ __launch_bounds__(256) void dinv_kernel(const int* __restrict__ counts, float* dinv) {
    int i = blockIdx.x * 256 + threadIdx.x;
    if (i < NNODES) dinv[i] = rsqrtf((float)(counts[i] + 1));   // +1 self loop
}

__global__ __launch_bounds__(256) void scan1_kernel(const int* __restrict__ counts,
                                                    int* __restrict__ offsets, int* __restrict__ bsum) {
    __shared__ int ls[256];
    const int b = blockIdx.x, t = threadIdx.x;
    const int base = b * 1024 + t * 4;
    int v0 = (base + 0 < NNODES) ? counts[base + 0] : 0;
    int v1 = (base + 1 < NNODES) ? counts[base + 1] : 0;
    int v2 = (base + 2 < NNODES) ? counts[base + 2] : 0;
    int v3 = (base + 3 < NNODES) ? counts[base + 3] : 0;
    ls[t] = v0 + v1 + v2 + v3;
    __syncthreads();
    for (int off = 1; off < 256; off <<= 1) {
        int v = (t >= off) ? ls[t - off] : 0;
        __syncthreads();
        ls[t] += v;
        __syncthreads();
    }
    int excl = (t == 0) ? 0 : ls[t - 1];
    if (t == 255) bsum[b] = ls[255];
    if (base + 0 < NNODES) offsets[base + 0] = excl;
    if (base + 1 < NNODES) offsets[base + 1] = excl + v0;
    if (base + 2 < NNODES) offsets[base + 2] = excl + v0 + v1;
    if (base + 3 < NNODES) offsets[base + 3] = excl + v0 + v1 + v2;
}

__global__ void scan2_kernel(int* bsum) {
    if (threadIdx.x == 0 && blockIdx.x == 0) {
        int s = 0;
        for (int b = 0; b < SCAN_NBLK; ++b) { int v = bsum[b]; bsum[b] = s; s += v; }
    }
}

__global__ __launch_bounds__(256) void scan3_kernel(int* __restrict__ offsets, const int* __restrict__ bsum) {
    const int b = blockIdx.x, t = threadIdx.x;
    const int add = bsum[b];
    const int base = b * 1024 + t * 4;
    #pragma unroll
    for (int i = 0; i < 4; ++i)
        if (base + i < NNODES) offsets[base + i] += add;
    if (b == 0 && t == 0) offsets[NNODES] = NEDGES;
}

__global__ __launch_bounds__(256)
void fill_kernel(const int* __restrict__ row, const int* __restrict__ col,
                 const float* __restrict__ dinv, const int* __restrict__ offsets,
                 int* __restrict__ cursor, int* __restrict__ eidx, float* __restrict__ ew) {
    int e = blockIdx.x * 256 + threadIdx.x;
    if (e >= NEDGES) return;
    int c = col[e], r = row[e];
    int p = offsets[c] + atomicAdd(&cursor[c], 1);
    eidx[p] = r;
    ew[p] = dinv[r] * dinv[c];
}

// S[c] = dinv[c]^2 * H[c] + sum_{e->c} w_e * H[row_e]; one wave per node (bf16 in/out)
__global__ __launch_bounds__(256)
void gather_b(const u16* __restrict__ Hb, const float* __restrict__ dinv,
              const int* __restrict__ offsets, const int* __restrict__ eidx,
              const float* __restrict__ ew, u16* __restrict__ Sb) {
    const int wid  = (blockIdx.x * 256 + threadIdx.x) >> 6;
    const int lane = threadIdx.x & 63;
    if (wid >= NNODES) return;
    float d = dinv[wid];
    unsigned hv = *(const unsigned*)&Hb[(size_t)wid * DH + lane * 2];
    float ax = d * d * b2f((u16)(hv & 0xFFFF));
    float ay = d * d * b2f((u16)(hv >> 16));
    const int s = offsets[wid], e = offsets[wid + 1];
    for (int p = s; p < e; ++p) {
        int r = eidx[p];
        float w = ew[p];
        unsigned h2 = *(const unsigned*)&Hb[(size_t)r * DH + lane * 2];
        ax = fmaf(w, b2f((u16)(h2 & 0xFFFF)), ax);
        ay = fmaf(w, b2f((u16)(h2 >> 16)), ay);
    }
    unsigned o = (unsigned)f2b(ax) | ((unsigned)f2b(ay) << 16);
    *(unsigned*)&Sb[(size_t)wid * DH + lane * 2] = o;
}

// ---------------- MFMA dense kernels ----------------
// Out[N x 128] = A[N x KD] @ B[KD x 128]; A direct global->frag, B staged in LDS
// (transposed + XOR-swizzled). AF=1: A is fp32 (converted in-reg). EPI=1:
// B is G; Out = relu(CZ*Hb + CS*Sb - CT*(A@G) + bias), all bf16 storage.
template<int KD, int AF, int EPI>
__global__ __launch_bounds__(256)
void mm_mfma(const void* __restrict__ Avoid, const float* __restrict__ Bf,
             u16* __restrict__ Out, const u16* __restrict__ Hb,
             const u16* __restrict__ Sb, const float* __restrict__ bias,
             int nrows)
{
    __shared__ __align__(16) u16 bt[128 * KD];   // bt[c*KD + (k ^ ((c&7)<<3))]
    const int t = threadIdx.x;
    const int w = t >> 6, l = t & 63;
    const int l15 = l & 15, g = l >> 4;
    const int row0 = blockIdx.x * 128 + w * 32;

    // stage B (fp32 [KD][128]) -> transposed bf16, swizzled
    for (int idx = t; idx < KD * 32; idx += 256) {
        int flat = idx * 4;
        int k = flat >> 7, c = flat & 127;
        float4 v = ((const float4*)Bf)[idx];
        bt[(c + 0) * KD + (k ^ (((c + 0) & 7) << 3))] = f2b(v.x);
        bt[(c + 1) * KD + (k ^ (((c + 1) & 7) << 3))] = f2b(v.y);
        bt[(c + 2) * KD + (k ^ (((c + 2) & 7) << 3))] = f2b(v.z);
        bt[(c + 3) * KD + (k ^ (((c + 3) & 7) << 3))] = f2b(v.w);
    }
    __syncthreads();

    const float* Af = (const float*)Avoid;
    const u16*   Ab = (const u16*)Avoid;
    int r[2];
    r[0] = min(row0 + l15,      nrows - 1);
    r[1] = min(row0 + 16 + l15, nrows - 1);

    f32x4 acc[2][8] = {};

    for (int k0 = 0; k0 < KD; k0 += 32) {
        s16x8 afr[2];
        #pragma unroll
        for (int m = 0; m < 2; ++m) {
            if (AF) {
                const float4* p = (const float4*)&Af[(size_t)r[m] * KD + k0 + g * 8];
                float4 u0 = p[0], u1 = p[1];
                s16x8 a;
                a[0] = (short)f2b(u0.x); a[1] = (short)f2b(u0.y);
                a[2] = (short)f2b(u0.z); a[3] = (short)f2b(u0.w);
                a[4] = (short)f2b(u1.x); a[5] = (short)f2b(u1.y);
                a[6] = (short)f2b(u1.z); a[7] = (short)f2b(u1.w);
                afr[m] = a;
            } else {
                afr[m] = *(const s16x8*)&Ab[(size_t)r[m] * KD + k0 + g * 8];
            }
        }
        const int kx = (k0 + g * 8) ^ ((l & 7) << 3);
        #pragma unroll
        for (int n = 0; n < 8; ++n) {
            s16x8 bfr = *(const s16x8*)&bt[(n * 16 + l15) * KD + kx];
            acc[0][n] = __builtin_amdgcn_mfma_f32_16x16x32_bf16(afr[0], bfr, acc[0][n], 0, 0, 0);
            acc[1][n] = __builtin_amdgcn_mfma_f32_16x16x32_bf16(afr[1], bfr, acc[1][n], 0, 0, 0);
        }
    }

    float bv[8];
    if (EPI) {
        #pragma unroll
        for (int n = 0; n < 8; ++n) bv[n] = bias[n * 16 + l15];
    }
    #pragma unroll
    for (int m = 0; m < 2; ++m) {
        #pragma unroll
        for (int j = 0; j < 4; ++j) {
            int grow = row0 + m * 16 + g * 4 + j;
            if (grow < nrows) {
                size_t base = (size_t)grow * 128;
                #pragma unroll
                for (int n = 0; n < 8; ++n) {
                    int col = n * 16 + l15;
                    float v = acc[m][n][j];
                    if (EPI) {
                        float h = b2f(Hb[base + col]);
                        float s = b2f(Sb[base + col]);
                        v = fmaxf(CZ * h + CS * s - CT * v + bv[n], 0.f);
                    }
                    Out[base + col] = f2b(v);
                }
            }
        }
    }
}

// Gram partials: P[b][128][128] = sum over this block's 64-row chunks of Hb^T Hb
__global__ __launch_bounds__(256)
void gram_mfma(const u16* __restrict__ Hb, float* __restrict__ P, int nrows)
{
    __shared__ __align__(16) u16 ht[2][128 * GCH];  // ht[c*GCH + (k ^ ((c&7)<<3))]
    const int t = threadIdx.x;
    const int w = t >> 6, l = t & 63;
    const int l15 = l & 15, g = l >> 4;
    const int nch = (nrows + GCH - 1) / GCH;

    f32x4 acc[2][8] = {};

    const int sr = t >> 2, sq = t & 3;   // staging: row sr, col-quarter sq

    // prologue stage
    {
        int gr = blockIdx.x * GCH + sr;
        #pragma unroll
        for (int i4 = 0; i4 < 4; ++i4) {
            int c0 = sq * 32 + i4 * 8;
            s16x8 v = {};
            if (gr < nrows) v = *(const s16x8*)&Hb[(size_t)gr * DH + c0];
            #pragma unroll
            for (int i = 0; i < 8; ++i) {
                int c = c0 + i;
                ht[0][c * GCH + (sr ^ ((c & 7) << 3))] = (u16)v[i];
            }
        }
    }
    __syncthreads();

    int buf = 0;
    for (int ch = blockIdx.x; ch < nch; ch += gridDim.x, buf ^= 1) {
        int chn = ch + gridDim.x;
        if (chn < nch) {   // stage next into other buffer
            int gr = chn * GCH + sr;
            #pragma unroll
            for (int i4 = 0; i4 < 4; ++i4) {
                int c0 = sq * 32 + i4 * 8;
                s16x8 v = {};
                if (gr < nrows) v = *(const s16x8*)&Hb[(size_t)gr * DH + c0];
                #pragma unroll
                for (int i = 0; i < 8; ++i) {
                    int c = c0 + i;
                    ht[buf ^ 1][c * GCH + (sr ^ ((c & 7) << 3))] = (u16)v[i];
                }
            }
        }
        #pragma unroll
        for (int ks = 0; ks < 2; ++ks) {
            const int kx = (ks * 32 + g * 8) ^ ((l & 7) << 3);
            s16x8 a0 = *(const s16x8*)&ht[buf][(w * 32 +      l15) * GCH + kx];
            s16x8 a1 = *(const s16x8*)&ht[buf][(w * 32 + 16 + l15) * GCH + kx];
            #pragma unroll
            for (int n = 0; n < 8; ++n) {
                s16x8 bfr = *(const s16x8*)&ht[buf][(n * 16 + l15) * GCH + kx];
                acc[0][n] = __builtin_amdgcn_mfma_f32_16x16x32_bf16(a0, bfr, acc[0][n], 0, 0, 0);
                acc[1][n] = __builtin_amdgcn_mfma_f32_16x16x32_bf16(a1, bfr, acc[1][n], 0, 0, 0);
            }
        }
        __syncthreads();
    }

    float* Pb = P + (size_t)blockIdx.x * (DH * DH);
    #pragma unroll
    for (int m = 0; m < 2; ++m)
        #pragma unroll
        for (int j = 0; j < 4; ++j) {
            int prow = w * 32 + m * 16 + g * 4 + j;
            #pragma unroll
            for (int n = 0; n < 8; ++n)
                Pb[prow * DH + n * 16 + l15] = acc[m][n][j];
        }
}

// deterministic reduce of partials -> G fp32
__global__ __launch_bounds__(256)
void gram_reduce(const float* __restrict__ P, float* __restrict__ G) {
    int idx = blockIdx.x * 256 + threadIdx.x;   // grid 64 -> 16384
    float s = 0.f;
    #pragma unroll 8
    for (int p = 0; p < GRAM_BLK; ++p)
        s += P[(size_t)p * (DH * DH) + idx];
    G[idx] = s;
}

// out[n] = log_softmax(Xb[n] @ Wf + bf); one wave per node, bf16 input
__global__ __launch_bounds__(256)
void fc_lsm_kernel(const u16* __restrict__ Xb, const float* __restrict__ Wf,
                   const float* __restrict__ bf, float* __restrict__ out, int nrows)
{
    __shared__ float xs[4][DH];
    const int w    = threadIdx.x >> 6;
    const int lane = threadIdx.x & 63;
    const int n    = blockIdx.x * 4 + w;
    if (n < nrows) {
        unsigned hv = *(const unsigned*)&Xb[(size_t)n * DH + lane * 2];
        xs[w][lane * 2]     = b2f((u16)(hv & 0xFFFF));
        xs[w][lane * 2 + 1] = b2f((u16)(hv >> 16));
    }
    __syncthreads();
    if (n >= nrows || lane >= KCLS) return;
    float acc = bf[lane];
    #pragma unroll 8
    for (int j = 0; j < DH; ++j)
        acc = fmaf(xs[w][j], Wf[j * KCLS + lane], acc);
    float m = acc;
    #pragma unroll
    for (int o = 8; o >= 1; o >>= 1)
        m = fmaxf(m, __shfl_xor(m, o, 16));
    float e = expf(acc - m);
    float ssum = e;
    #pragma unroll
    for (int o = 8; o >= 1; o >>= 1)
        ssum += __shfl_xor(ssum, o, 16);
    out[(size_t)n * KCLS + lane] = acc - m - logf(ssum);
}

extern "C" void kernel_launch(void* const* d_in, const int* in_sizes, int n_in,
                              void* d_out, int out_size, void* d_ws, size_t ws_size,
                              hipStream_t stream) {
    const float* x  = (const float*)d_in[0];
    const int*   ei = (const int*)d_in[1];
    const float* W1 = (const float*)d_in[2];
    const float* b1 = (const float*)d_in[3];
    const float* W2 = (const float*)d_in[4];
    const float* b2 = (const float*)d_in[5];
    const float* Wf = (const float*)d_in[6];
    const float* bf = (const float*)d_in[7];
    float* out = (float*)d_out;

    const int* row = ei;            // edge_index[0] = source
    const int* col = ei + NEDGES;   // edge_index[1] = target

    float* dinv    = (float*)d_ws;                      // 102400 floats
    float* G       = dinv + 102400;                     // 16384
    float* P       = G + 16384;                         // 256*16384
    int*   counts  = (int*)(P + (size_t)GRAM_BLK * DH * DH);  // 102400
    int*   offsets = counts + 102400;                   // 102656
    int*   bsum    = offsets + 102656;                  // 128
    int*   eidx    = bsum + 128;                        // E
    float* ew      = (float*)(eidx + NEDGES);           // E
    u16*   B0b     = (u16*)(ew + NEDGES);               // N*128 bf16
    u16*   B1b     = B0b + (size_t)NNODES * DH;
    u16*   Sb      = B1b + (size_t)NNODES * DH;

    dim3 b256(256);
    const int gN  = (NNODES + 255) / 256;
    const int gE  = (NEDGES + 255) / 256;
    const int gMM = (NNODES + 127) / 128;         // 782
    const int gGA = (NNODES * 64 + 255) / 256;    // gather: 1 wave/node

    // ---- degrees + CSR build ----
    hipMemsetAsync(counts, 0, NNODES * sizeof(int), stream);
    hist_kernel<<<gE, b256, 0, stream>>>(col, counts);
    dinv_kernel<<<gN, b256, 0, stream>>>(counts, dinv);
    scan1_kernel<<<SCAN_NBLK, b256, 0, stream>>>(counts, offsets, bsum);
    scan2_kernel<<<1, 64, 0, stream>>>(bsum);
    scan3_kernel<<<SCAN_NBLK, b256, 0, stream>>>(offsets, bsum);
    hipMemsetAsync(counts, 0, NNODES * sizeof(int), stream);   // reuse as cursor
    fill_kernel<<<gE, b256, 0, stream>>>(row, col, dinv, offsets, counts, eidx, ew);

    // ---- layer 1 ----
    mm_mfma<DIN, 1, 0><<<gMM, b256, 0, stream>>>(x, W1, B0b, nullptr, nullptr, nullptr, NNODES);
    gram_mfma<<<GRAM_BLK, b256, 0, stream>>>(B0b, P, NNODES);
    gram_reduce<<<64, b256, 0, stream>>>(P, G);
    gather_b<<<gGA, b256, 0, stream>>>(B0b, dinv, offsets, eidx, ew, Sb);
    mm_mfma<DH, 0, 1><<<gMM, b256, 0, stream>>>(B0b, G, B1b, B0b, Sb, b1, NNODES);

    // ---- layer 2 ----
    mm_mfma<DH, 0, 0><<<gMM, b256, 0, stream>>>(B1b, W2, B0b, nullptr, nullptr, nullptr, NNODES);
    gram_mfma<<<GRAM_BLK, b256, 0, stream>>>(B0b, P, NNODES);
    gram_reduce<<<64, b256, 0, stream>>>(P, G);
    gather_b<<<gGA, b256, 0, stream>>>(B0b, dinv, offsets, eidx, ew, Sb);
    mm_mfma<DH, 0, 1><<<gMM, b256, 0, stream>>>(B0b, G, B1b, B0b, Sb, b2, NNODES);

    // ---- fc + log_softmax ----
    fc_lsm_kernel<<<(NNODES + 3) / 4, b256, 0, stream>>>(B1b, Wf, bf, out, NNODES);
}

// Round 5
// 459.223 us; speedup vs baseline: 3.5481x; 1.1733x over previous
//
#include <hip/hip_runtime.h>

#define NNODES 100000
#define NEDGES 800000
#define DIN    256
#define DH     128
#define KCLS   16
#define SCAN_NBLK 98   // ceil(100000/1024)
#define GCH 64         // gram K-chunk rows
#define GRAM_BLK 256   // gram partial blocks

typedef unsigned short u16;
typedef short s16x8 __attribute__((ext_vector_type(8)));
typedef float f32x4 __attribute__((ext_vector_type(4)));

static constexpr float CZ = 0.95f;   // 1 - gamma*l1 + gamma*l2
static constexpr float CS = 0.10f;   // gamma*l1
static constexpr float CT = 0.05f;   // gamma*l2

__device__ __forceinline__ u16 f2b(float f) {           // fp32 -> bf16 RNE
    unsigned u = __builtin_bit_cast(unsigned, f);
    return (u16)((u + 0x7FFFu + ((u >> 16) & 1u)) >> 16);
}
__device__ __forceinline__ float b2f(u16 b) {
    return __builtin_bit_cast(float, ((unsigned)b) << 16);
}

// ---------------- degree / CSR build ----------------

__global__ __launch_bounds__(256) void hist_kernel(const int* __restrict__ col, int* counts) {
    int i = blockIdx.x * 256 + threadIdx.x;
    if (i < NEDGES) atomicAdd(&counts[col[i]], 1);
}

__global__ __launch_bounds__(256) void dinv_kernel(const int* __restrict__ counts, float* dinv) {
    int i = blockIdx.x * 256 + threadIdx.x;
    if (i < NNODES) dinv[i] = rsqrtf((float)(counts[i] + 1));   // +1 self loop
}

__global__ __launch_bounds__(256) void scan1_kernel(const int* __restrict__ counts,
                                                    int* __restrict__ offsets, int* __restrict__ bsum) {
    __shared__ int ls[256];
    const int b = blockIdx.x, t = threadIdx.x;
    const int base = b * 1024 + t * 4;
    int v0 = (base + 0 < NNODES) ? counts[base + 0] : 0;
    int v1 = (base + 1 < NNODES) ? counts[base + 1] : 0;
    int v2 = (base + 2 < NNODES) ? counts[base + 2] : 0;
    int v3 = (base + 3 < NNODES) ? counts[base + 3] : 0;
    ls[t] = v0 + v1 + v2 + v3;
    __syncthreads();
    for (int off = 1; off < 256; off <<= 1) {
        int v = (t >= off) ? ls[t - off] : 0;
        __syncthreads();
        ls[t] += v;
        __syncthreads();
    }
    int excl = (t == 0) ? 0 : ls[t - 1];
    if (t == 255) bsum[b] = ls[255];
    if (base + 0 < NNODES) offsets[base + 0] = excl;
    if (base + 1 < NNODES) offsets[base + 1] = excl + v0;
    if (base + 2 < NNODES) offsets[base + 2] = excl + v0 + v1;
    if (base + 3 < NNODES) offsets[base + 3] = excl + v0 + v1 + v2;
}

__global__ void scan2_kernel(int* bsum) {
    if (threadIdx.x == 0 && blockIdx.x == 0) {
        int s = 0;
        for (int b = 0; b < SCAN_NBLK; ++b) { int v = bsum[b]; bsum[b] = s; s += v; }
    }
}

__global__ __launch_bounds__(256) void scan3_kernel(int* __restrict__ offsets, const int* __restrict__ bsum) {
    const int b = blockIdx.x, t = threadIdx.x;
    const int add = bsum[b];
    const int base = b * 1024 + t * 4;
    #pragma unroll
    for (int i = 0; i < 4; ++i)
        if (base + i < NNODES) offsets[base + i] += add;
    if (b == 0 && t == 0) offsets[NNODES] = NEDGES;
}

__global__ __launch_bounds__(256)
void fill_kernel(const int* __restrict__ row, const int* __restrict__ col,
                 const float* __restrict__ dinv, const int* __restrict__ offsets,
                 int* __restrict__ cursor, int* __restrict__ eidx, float* __restrict__ ew) {
    int e = blockIdx.x * 256 + threadIdx.x;
    if (e >= NEDGES) return;
    int c = col[e], r = row[e];
    int p = offsets[c] + atomicAdd(&cursor[c], 1);
    eidx[p] = r;
    ew[p] = dinv[r] * dinv[c];
}

// S[c] = dinv[c]^2 * H[c] + sum_{e->c} w_e * H[row_e]; one wave per node (bf16 in/out)
__global__ __launch_bounds__(256)
void gather_b(const u16* __restrict__ Hb, const float* __restrict__ dinv,
              const int* __restrict__ offsets, const int* __restrict__ eidx,
              const float* __restrict__ ew, u16* __restrict__ Sb) {
    const int wid  = (blockIdx.x * 256 + threadIdx.x) >> 6;
    const int lane = threadIdx.x & 63;
    if (wid >= NNODES) return;
    float d = dinv[wid];
    unsigned hv = *(const unsigned*)&Hb[(size_t)wid * DH + lane * 2];
    float ax = d * d * b2f((u16)(hv & 0xFFFF));
    float ay = d * d * b2f((u16)(hv >> 16));
    const int s = offsets[wid], e = offsets[wid + 1];
    for (int p = s; p < e; ++p) {
        int r = eidx[p];
        float w = ew[p];
        unsigned h2 = *(const unsigned*)&Hb[(size_t)r * DH + lane * 2];
        ax = fmaf(w, b2f((u16)(h2 & 0xFFFF)), ax);
        ay = fmaf(w, b2f((u16)(h2 >> 16)), ay);
    }
    unsigned o = (unsigned)f2b(ax) | ((unsigned)f2b(ay) << 16);
    *(unsigned*)&Sb[(size_t)wid * DH + lane * 2] = o;
}

// ---------------- MFMA dense kernels ----------------
// Out[N x 128] = A[N x KD] @ B[KD x 128]; A direct global->frag, B staged in LDS
// (transposed + XOR-swizzled). AF=1: A is fp32 (converted in-reg). EPI=1:
// B is G; Out = relu(CZ*Hb + CS*Sb - CT*(A@G) + bias), all bf16 storage.
template<int KD, int AF, int EPI>
__global__ __launch_bounds__(256)
void mm_mfma(const void* __restrict__ Avoid, const float* __restrict__ Bf,
             u16* __restrict__ Out, const u16* __restrict__ Hb,
             const u16* __restrict__ Sb, const float* __restrict__ bias,
             int nrows)
{
    __shared__ __align__(16) u16 bt[128 * KD];   // bt[c*KD + (k ^ ((c&7)<<3))]
    const int t = threadIdx.x;
    const int w = t >> 6, l = t & 63;
    const int l15 = l & 15, g = l >> 4;
    const int row0 = blockIdx.x * 128 + w * 32;

    // stage B (fp32 [KD][128]) -> transposed bf16, swizzled
    for (int idx = t; idx < KD * 32; idx += 256) {
        int flat = idx * 4;
        int k = flat >> 7, c = flat & 127;
        float4 v = ((const float4*)Bf)[idx];
        bt[(c + 0) * KD + (k ^ (((c + 0) & 7) << 3))] = f2b(v.x);
        bt[(c + 1) * KD + (k ^ (((c + 1) & 7) << 3))] = f2b(v.y);
        bt[(c + 2) * KD + (k ^ (((c + 2) & 7) << 3))] = f2b(v.z);
        bt[(c + 3) * KD + (k ^ (((c + 3) & 7) << 3))] = f2b(v.w);
    }
    __syncthreads();

    const float* Af = (const float*)Avoid;
    const u16*   Ab = (const u16*)Avoid;
    int r[2];
    r[0] = min(row0 + l15,      nrows - 1);
    r[1] = min(row0 + 16 + l15, nrows - 1);

    f32x4 acc[2][8] = {};

    for (int k0 = 0; k0 < KD; k0 += 32) {
        s16x8 afr[2];
        #pragma unroll
        for (int m = 0; m < 2; ++m) {
            if (AF) {
                const float4* p = (const float4*)&Af[(size_t)r[m] * KD + k0 + g * 8];
                float4 u0 = p[0], u1 = p[1];
                s16x8 a;
                a[0] = (short)f2b(u0.x); a[1] = (short)f2b(u0.y);
                a[2] = (short)f2b(u0.z); a[3] = (short)f2b(u0.w);
                a[4] = (short)f2b(u1.x); a[5] = (short)f2b(u1.y);
                a[6] = (short)f2b(u1.z); a[7] = (short)f2b(u1.w);
                afr[m] = a;
            } else {
                afr[m] = *(const s16x8*)&Ab[(size_t)r[m] * KD + k0 + g * 8];
            }
        }
        const int kx = (k0 + g * 8) ^ ((l & 7) << 3);
        #pragma unroll
        for (int n = 0; n < 8; ++n) {
            s16x8 bfr = *(const s16x8*)&bt[(n * 16 + l15) * KD + kx];
            acc[0][n] = __builtin_amdgcn_mfma_f32_16x16x32_bf16(afr[0], bfr, acc[0][n], 0, 0, 0);
            acc[1][n] = __builtin_amdgcn_mfma_f32_16x16x32_bf16(afr[1], bfr, acc[1][n], 0, 0, 0);
        }
    }

    float bv[8];
    if (EPI) {
        #pragma unroll
        for (int n = 0; n < 8; ++n) bv[n] = bias[n * 16 + l15];
    }
    #pragma unroll
    for (int m = 0; m < 2; ++m) {
        #pragma unroll
        for (int j = 0; j < 4; ++j) {
            int grow = row0 + m * 16 + g * 4 + j;
            if (grow < nrows) {
                size_t base = (size_t)grow * 128;
                #pragma unroll
                for (int n = 0; n < 8; ++n) {
                    int col = n * 16 + l15;
                    float v = acc[m][n][j];
                    if (EPI) {
                        float h = b2f(Hb[base + col]);
                        float s = b2f(Sb[base + col]);
                        v = fmaxf(CZ * h + CS * s - CT * v + bv[n], 0.f);
                    }
                    Out[base + col] = f2b(v);
                }
            }
        }
    }
}

// Gram partials: P[b][128][128] = sum over this block's 64-row chunks of Hb^T Hb
__global__ __launch_bounds__(256)
void gram_mfma(const u16* __restrict__ Hb, float* __restrict__ P, int nrows)
{
    __shared__ __align__(16) u16 ht[2][128 * GCH];  // ht[c*GCH + (k ^ ((c&7)<<3))]
    const int t = threadIdx.x;
    const int w = t >> 6, l = t & 63;
    const int l15 = l & 15, g = l >> 4;
    const int nch = (nrows + GCH - 1) / GCH;

    f32x4 acc[2][8] = {};

    const int sr = t >> 2, sq = t & 3;   // staging: row sr, col-quarter sq

    // prologue stage
    {
        int gr = blockIdx.x * GCH + sr;
        #pragma unroll
        for (int i4 = 0; i4 < 4; ++i4) {
            int c0 = sq * 32 + i4 * 8;
            s16x8 v = {};
            if (gr < nrows) v = *(const s16x8*)&Hb[(size_t)gr * DH + c0];
            #pragma unroll
            for (int i = 0; i < 8; ++i) {
                int c = c0 + i;
                ht[0][c * GCH + (sr ^ ((c & 7) << 3))] = (u16)v[i];
            }
        }
    }
    __syncthreads();

    int buf = 0;
    for (int ch = blockIdx.x; ch < nch; ch += gridDim.x, buf ^= 1) {
        int chn = ch + gridDim.x;
        if (chn < nch) {   // stage next into other buffer
            int gr = chn * GCH + sr;
            #pragma unroll
            for (int i4 = 0; i4 < 4; ++i4) {
                int c0 = sq * 32 + i4 * 8;
                s16x8 v = {};
                if (gr < nrows) v = *(const s16x8*)&Hb[(size_t)gr * DH + c0];
                #pragma unroll
                for (int i = 0; i < 8; ++i) {
                    int c = c0 + i;
                    ht[buf ^ 1][c * GCH + (sr ^ ((c & 7) << 3))] = (u16)v[i];
                }
            }
        }
        #pragma unroll
        for (int ks = 0; ks < 2; ++ks) {
            const int kx = (ks * 32 + g * 8) ^ ((l & 7) << 3);
            s16x8 a0 = *(const s16x8*)&ht[buf][(w * 32 +      l15) * GCH + kx];
            s16x8 a1 = *(const s16x8*)&ht[buf][(w * 32 + 16 + l15) * GCH + kx];
            #pragma unroll
            for (int n = 0; n < 8; ++n) {
                s16x8 bfr = *(const s16x8*)&ht[buf][(n * 16 + l15) * GCH + kx];
                acc[0][n] = __builtin_amdgcn_mfma_f32_16x16x32_bf16(a0, bfr, acc[0][n], 0, 0, 0);
                acc[1][n] = __builtin_amdgcn_mfma_f32_16x16x32_bf16(a1, bfr, acc[1][n], 0, 0, 0);
            }
        }
        __syncthreads();
    }

    float* Pb = P + (size_t)blockIdx.x * (DH * DH);
    #pragma unroll
    for (int m = 0; m < 2; ++m)
        #pragma unroll
        for (int j = 0; j < 4; ++j) {
            int prow = w * 32 + m * 16 + g * 4 + j;
            #pragma unroll
            for (int n = 0; n < 8; ++n)
                Pb[prow * DH + n * 16 + l15] = acc[m][n][j];
        }
}

// deterministic reduce of partials -> G fp32
__global__ __launch_bounds__(256)
void gram_reduce(const float* __restrict__ P, float* __restrict__ G) {
    int idx = blockIdx.x * 256 + threadIdx.x;   // grid 64 -> 16384
    float s = 0.f;
    #pragma unroll 8
    for (int p = 0; p < GRAM_BLK; ++p)
        s += P[(size_t)p * (DH * DH) + idx];
    G[idx] = s;
}

// FC + log_softmax via MFMA: logits = Xb @ Wf + bf, then in-register softmax.
// 4 waves/block, 32 rows/wave. Wf staged in LDS transposed+swizzled bf16.
__global__ __launch_bounds__(256)
void fc_mfma(const u16* __restrict__ Xb, const float* __restrict__ Wf,
             const float* __restrict__ bf, float* __restrict__ out, int nrows)
{
    __shared__ __align__(16) u16 wt[KCLS * DH];   // wt[c*128 + (k ^ ((c&7)<<3))]
    const int t = threadIdx.x;
    const int w = t >> 6, l = t & 63;
    const int l15 = l & 15, g = l >> 4;
    const int row0 = blockIdx.x * 128 + w * 32;

    // stage Wf (fp32 [128][16]) -> wt bf16 transposed, swizzled (2048 elems)
    for (int idx = t; idx < KCLS * DH; idx += 256) {
        int c = idx >> 7, k = idx & 127;
        wt[c * DH + (k ^ ((c & 7) << 3))] = f2b(Wf[k * KCLS + c]);
    }
    __syncthreads();

    int r[2];
    r[0] = min(row0 + l15,      nrows - 1);
    r[1] = min(row0 + 16 + l15, nrows - 1);

    f32x4 acc[2] = {};
    #pragma unroll
    for (int k0 = 0; k0 < DH; k0 += 32) {
        s16x8 a0 = *(const s16x8*)&Xb[(size_t)r[0] * DH + k0 + g * 8];
        s16x8 a1 = *(const s16x8*)&Xb[(size_t)r[1] * DH + k0 + g * 8];
        s16x8 bfr = *(const s16x8*)&wt[l15 * DH + ((k0 + g * 8) ^ ((l & 7) << 3))];
        acc[0] = __builtin_amdgcn_mfma_f32_16x16x32_bf16(a0, bfr, acc[0], 0, 0, 0);
        acc[1] = __builtin_amdgcn_mfma_f32_16x16x32_bf16(a1, bfr, acc[1], 0, 0, 0);
    }

    const float bias = bf[l15];
    #pragma unroll
    for (int m = 0; m < 2; ++m) {
        #pragma unroll
        for (int j = 0; j < 4; ++j) {
            int grow = row0 + m * 16 + g * 4 + j;
            float v = acc[m][j] + bias;
            // row's 16 logits live in this 16-lane group: reduce via shfl_xor
            float mx = v;
            #pragma unroll
            for (int o = 8; o >= 1; o >>= 1)
                mx = fmaxf(mx, __shfl_xor(mx, o));
            float e = expf(v - mx);
            float ssum = e;
            #pragma unroll
            for (int o = 8; o >= 1; o >>= 1)
                ssum += __shfl_xor(ssum, o);
            if (grow < nrows)
                out[(size_t)grow * KCLS + l15] = v - mx - logf(ssum);
        }
    }
}

extern "C" void kernel_launch(void* const* d_in, const int* in_sizes, int n_in,
                              void* d_out, int out_size, void* d_ws, size_t ws_size,
                              hipStream_t stream) {
    const float* x  = (const float*)d_in[0];
    const int*   ei = (const int*)d_in[1];
    const float* W1 = (const float*)d_in[2];
    const float* b1 = (const float*)d_in[3];
    const float* W2 = (const float*)d_in[4];
    const float* b2 = (const float*)d_in[5];
    const float* Wf = (const float*)d_in[6];
    const float* bf = (const float*)d_in[7];
    float* out = (float*)d_out;

    const int* row = ei;            // edge_index[0] = source
    const int* col = ei + NEDGES;   // edge_index[1] = target

    float* dinv    = (float*)d_ws;                      // 102400 floats
    float* G       = dinv + 102400;                     // 16384
    float* P       = G + 16384;                         // 256*16384
    int*   counts  = (int*)(P + (size_t)GRAM_BLK * DH * DH);  // 102400
    int*   offsets = counts + 102400;                   // 102656
    int*   bsum    = offsets + 102656;                  // 128
    int*   eidx    = bsum + 128;                        // E
    float* ew      = (float*)(eidx + NEDGES);           // E
    u16*   B0b     = (u16*)(ew + NEDGES);               // N*128 bf16
    u16*   B1b     = B0b + (size_t)NNODES * DH;
    u16*   Sb      = B1b + (size_t)NNODES * DH;

    dim3 b256(256);
    const int gN  = (NNODES + 255) / 256;
    const int gE  = (NEDGES + 255) / 256;
    const int gMM = (NNODES + 127) / 128;         // 782
    const int gGA = (NNODES * 64 + 255) / 256;    // gather: 1 wave/node

    // ---- degrees + CSR build ----
    hipMemsetAsync(counts, 0, NNODES * sizeof(int), stream);
    hist_kernel<<<gE, b256, 0, stream>>>(col, counts);
    dinv_kernel<<<gN, b256, 0, stream>>>(counts, dinv);
    scan1_kernel<<<SCAN_NBLK, b256, 0, stream>>>(counts, offsets, bsum);
    scan2_kernel<<<1, 64, 0, stream>>>(bsum);
    scan3_kernel<<<SCAN_NBLK, b256, 0, stream>>>(offsets, bsum);
    hipMemsetAsync(counts, 0, NNODES * sizeof(int), stream);   // reuse as cursor
    fill_kernel<<<gE, b256, 0, stream>>>(row, col, dinv, offsets, counts, eidx, ew);

    // ---- layer 1 ----
    mm_mfma<DIN, 1, 0><<<gMM, b256, 0, stream>>>(x, W1, B0b, nullptr, nullptr, nullptr, NNODES);
    gram_mfma<<<GRAM_BLK, b256, 0, stream>>>(B0b, P, NNODES);
    gram_reduce<<<64, b256, 0, stream>>>(P, G);
    gather_b<<<gGA, b256, 0, stream>>>(B0b, dinv, offsets, eidx, ew, Sb);
    mm_mfma<DH, 0, 1><<<gMM, b256, 0, stream>>>(B0b, G, B1b, B0b, Sb, b1, NNODES);

    // ---- layer 2 ----
    mm_mfma<DH, 0, 0><<<gMM, b256, 0, stream>>>(B1b, W2, B0b, nullptr, nullptr, nullptr, NNODES);
    gram_mfma<<<GRAM_BLK, b256, 0, stream>>>(B0b, P, NNODES);
    gram_reduce<<<64, b256, 0, stream>>>(P, G);
    gather_b<<<gGA, b256, 0, stream>>>(B0b, dinv, offsets, eidx, ew, Sb);
    mm_mfma<DH, 0, 1><<<gMM, b256, 0, stream>>>(B0b, G, B1b, B0b, Sb, b2, NNODES);

    // ---- fc + log_softmax (MFMA) ----
    fc_mfma<<<gMM, b256, 0, stream>>>(B1b, Wf, bf, out, NNODES);
}

// Round 6
// 422.261 us; speedup vs baseline: 3.8587x; 1.0875x over previous
//
#include <hip/hip_runtime.h>

#define NNODES 100000
#define NEDGES 800000
#define DIN    256
#define DH     128
#define KCLS   16
#define SCAN_NBLK 98   // ceil(100000/1024)
#define GCH 64         // gram K-chunk rows
#define GRAM_BLK 256   // gram partial blocks

typedef unsigned short u16;
typedef short s16x8 __attribute__((ext_vector_type(8)));
typedef float f32x4 __attribute__((ext_vector_type(4)));

static constexpr float CZ = 0.95f;   // 1 - gamma*l1 + gamma*l2
static constexpr float CS = 0.10f;   // gamma*l1
static constexpr float CT = 0.05f;   // gamma*l2

__device__ __forceinline__ u16 f2b(float f) {           // fp32 -> bf16 RNE
    unsigned u = __builtin_bit_cast(unsigned, f);
    return (u16)((u + 0x7FFFu + ((u >> 16) & 1u)) >> 16);
}
__device__ __forceinline__ float b2f(u16 b) {
    return __builtin_bit_cast(float, ((unsigned)b) << 16);
}

// ---------------- degree / CSR build ----------------

__global__ __launch_bounds__(256) void hist_kernel(const int* __restrict__ col, int* counts) {
    int i = blockIdx.x * 256 + threadIdx.x;
    if (i < NEDGES) atomicAdd(&counts[col[i]], 1);
}

__global__ __launch_bounds__(256) void dinv_kernel(const int* __restrict__ counts, float* dinv) {
    int i = blockIdx.x * 256 + threadIdx.x;
    if (i < NNODES) dinv[i] = rsqrtf((float)(counts[i] + 1));   // +1 self loop
}

__global__ __launch_bounds__(256) void scan1_kernel(const int* __restrict__ counts,
                                                    int* __restrict__ offsets, int* __restrict__ bsum) {
    __shared__ int ls[256];
    const int b = blockIdx.x, t = threadIdx.x;
    const int base = b * 1024 + t * 4;
    int v0 = (base + 0 < NNODES) ? counts[base + 0] : 0;
    int v1 = (base + 1 < NNODES) ? counts[base + 1] : 0;
    int v2 = (base + 2 < NNODES) ? counts[base + 2] : 0;
    int v3 = (base + 3 < NNODES) ? counts[base + 3] : 0;
    ls[t] = v0 + v1 + v2 + v3;
    __syncthreads();
    for (int off = 1; off < 256; off <<= 1) {
        int v = (t >= off) ? ls[t - off] : 0;
        __syncthreads();
        ls[t] += v;
        __syncthreads();
    }
    int excl = (t == 0) ? 0 : ls[t - 1];
    if (t == 255) bsum[b] = ls[255];
    if (base + 0 < NNODES) offsets[base + 0] = excl;
    if (base + 1 < NNODES) offsets[base + 1] = excl + v0;
    if (base + 2 < NNODES) offsets[base + 2] = excl + v0 + v1;
    if (base + 3 < NNODES) offsets[base + 3] = excl + v0 + v1 + v2;
}

__global__ void scan2_kernel(int* bsum) {
    if (threadIdx.x == 0 && blockIdx.x == 0) {
        int s = 0;
        for (int b = 0; b < SCAN_NBLK; ++b) { int v = bsum[b]; bsum[b] = s; s += v; }
    }
}

__global__ __launch_bounds__(256) void scan3_kernel(int* __restrict__ offsets, const int* __restrict__ bsum) {
    const int b = blockIdx.x, t = threadIdx.x;
    const int add = bsum[b];
    const int base = b * 1024 + t * 4;
    #pragma unroll
    for (int i = 0; i < 4; ++i)
        if (base + i < NNODES) offsets[base + i] += add;
    if (b == 0 && t == 0) offsets[NNODES] = NEDGES;
}

__global__ __launch_bounds__(256)
void fill_kernel(const int* __restrict__ row, const int* __restrict__ col,
                 const float* __restrict__ dinv, const int* __restrict__ offsets,
                 int* __restrict__ cursor, int* __restrict__ eidx, float* __restrict__ ew) {
    int e = blockIdx.x * 256 + threadIdx.x;
    if (e >= NEDGES) return;
    int c = col[e], r = row[e];
    int p = offsets[c] + atomicAdd(&cursor[c], 1);
    eidx[p] = r;
    ew[p] = dinv[r] * dinv[c];
}

// S[c] = dinv[c]^2 * H[c] + sum_{e->c} w_e * H[row_e]; one wave per node (bf16 in/out)
__global__ __launch_bounds__(256)
void gather_b(const u16* __restrict__ Hb, const float* __restrict__ dinv,
              const int* __restrict__ offsets, const int* __restrict__ eidx,
              const float* __restrict__ ew, u16* __restrict__ Sb) {
    const int wid  = (blockIdx.x * 256 + threadIdx.x) >> 6;
    const int lane = threadIdx.x & 63;
    if (wid >= NNODES) return;
    float d = dinv[wid];
    unsigned hv = *(const unsigned*)&Hb[(size_t)wid * DH + lane * 2];
    float ax = d * d * b2f((u16)(hv & 0xFFFF));
    float ay = d * d * b2f((u16)(hv >> 16));
    const int s = offsets[wid], e = offsets[wid + 1];
    for (int p = s; p < e; ++p) {
        int r = eidx[p];
        float w = ew[p];
        unsigned h2 = *(const unsigned*)&Hb[(size_t)r * DH + lane * 2];
        ax = fmaf(w, b2f((u16)(h2 & 0xFFFF)), ax);
        ay = fmaf(w, b2f((u16)(h2 >> 16)), ay);
    }
    unsigned o = (unsigned)f2b(ax) | ((unsigned)f2b(ay) << 16);
    *(unsigned*)&Sb[(size_t)wid * DH + lane * 2] = o;
}

// ---------------- prep kernels ----------------

// x fp32 -> bf16, vectorized (float4 x2 -> s16x8)
__global__ __launch_bounds__(256)
void cvt_x_kernel(const float* __restrict__ x, u16* __restrict__ xb) {
    const long total = (long)NNODES * DIN / 8;
    for (long i = blockIdx.x * 256L + threadIdx.x; i < total; i += (long)gridDim.x * 256) {
        const float4* p = (const float4*)&x[i * 8];
        float4 u0 = p[0], u1 = p[1];
        s16x8 v;
        v[0] = (short)f2b(u0.x); v[1] = (short)f2b(u0.y);
        v[2] = (short)f2b(u0.z); v[3] = (short)f2b(u0.w);
        v[4] = (short)f2b(u1.x); v[5] = (short)f2b(u1.y);
        v[6] = (short)f2b(u1.z); v[7] = (short)f2b(u1.w);
        *(s16x8*)&xb[i * 8] = v;
    }
}

// W fp32 [KD][128] -> Wt bf16 [128][KD]
template<int KD>
__global__ __launch_bounds__(256)
void tr_w_kernel(const float* __restrict__ W, u16* __restrict__ Wt) {
    int idx = blockIdx.x * 256 + threadIdx.x;
    if (idx < 128 * KD) {
        int c = idx / KD, k = idx % KD;
        Wt[idx] = f2b(W[k * 128 + c]);
    }
}

// ---------------- MFMA dense kernels ----------------
// Out[N x 128] = A[N x KD] @ B[KD x 128], A bf16 row-major, Bt bf16 [c][k].
// Canonical staged structure: per-32k-chunk double-buffered LDS tiles
// (padded stride 40 elems -> <=2-way bank aliasing), b128 everywhere.
// EPI=1: Bt is G; Out = relu(CZ*Hb + CS*Sb - CT*(A@G) + bias).
template<int KD, int EPI>
__global__ __launch_bounds__(256, 4)
void mm_bt(const u16* __restrict__ A, const u16* __restrict__ Bt,
           u16* __restrict__ Out, const u16* __restrict__ Hb,
           const u16* __restrict__ Sb, const float* __restrict__ bias,
           int nrows)
{
    __shared__ __align__(16) u16 as_[2][128 * 40];
    __shared__ __align__(16) u16 bs_[2][128 * 40];
    const int t = threadIdx.x;
    const int w = t >> 6, l = t & 63;
    const int l15 = l & 15, g = l >> 4;
    const int row0 = blockIdx.x * 128;

    const int sr = t >> 2, so = t & 3;   // staging: row (0..63), k-octet (0..3)
    int arow[2];
    arow[0] = min(row0 + sr,      nrows - 1);
    arow[1] = min(row0 + 64 + sr, nrows - 1);

    // prologue: stage chunk 0 into buf 0
    #pragma unroll
    for (int i = 0; i < 2; ++i) {
        s16x8 va = *(const s16x8*)&A [(size_t)arow[i] * KD + so * 8];
        s16x8 vb = *(const s16x8*)&Bt[(size_t)(sr + i * 64) * KD + so * 8];
        *(s16x8*)&as_[0][(sr + i * 64) * 40 + so * 8] = va;
        *(s16x8*)&bs_[0][(sr + i * 64) * 40 + so * 8] = vb;
    }
    __syncthreads();

    f32x4 acc[2][8] = {};
    constexpr int NK = KD / 32;

    for (int kc = 0; kc < NK; ++kc) {
        const int buf = kc & 1;
        // issue next chunk's global loads early (hide under MFMA)
        s16x8 va[2], vb[2];
        const bool pf = (kc + 1 < NK);
        if (pf) {
            const int k0 = (kc + 1) * 32;
            #pragma unroll
            for (int i = 0; i < 2; ++i) {
                va[i] = *(const s16x8*)&A [(size_t)arow[i] * KD + k0 + so * 8];
                vb[i] = *(const s16x8*)&Bt[(size_t)(sr + i * 64) * KD + k0 + so * 8];
            }
        }
        // compute current chunk
        s16x8 af0 = *(const s16x8*)&as_[buf][(w * 32 +      l15) * 40 + g * 8];
        s16x8 af1 = *(const s16x8*)&as_[buf][(w * 32 + 16 + l15) * 40 + g * 8];
        #pragma unroll
        for (int n = 0; n < 8; ++n) {
            s16x8 bfr = *(const s16x8*)&bs_[buf][(n * 16 + l15) * 40 + g * 8];
            acc[0][n] = __builtin_amdgcn_mfma_f32_16x16x32_bf16(af0, bfr, acc[0][n], 0, 0, 0);
            acc[1][n] = __builtin_amdgcn_mfma_f32_16x16x32_bf16(af1, bfr, acc[1][n], 0, 0, 0);
        }
        // write next chunk into the other buffer
        if (pf) {
            #pragma unroll
            for (int i = 0; i < 2; ++i) {
                *(s16x8*)&as_[buf ^ 1][(sr + i * 64) * 40 + so * 8] = va[i];
                *(s16x8*)&bs_[buf ^ 1][(sr + i * 64) * 40 + so * 8] = vb[i];
            }
        }
        __syncthreads();
    }

    float bv[8];
    if (EPI) {
        #pragma unroll
        for (int n = 0; n < 8; ++n) bv[n] = bias[n * 16 + l15];
    }
    #pragma unroll
    for (int m = 0; m < 2; ++m) {
        #pragma unroll
        for (int j = 0; j < 4; ++j) {
            int grow = row0 + w * 32 + m * 16 + g * 4 + j;
            if (grow < nrows) {
                size_t base = (size_t)grow * 128;
                #pragma unroll
                for (int n = 0; n < 8; ++n) {
                    int col = n * 16 + l15;
                    float v = acc[m][n][j];
                    if (EPI) {
                        float h = b2f(Hb[base + col]);
                        float s = b2f(Sb[base + col]);
                        v = fmaxf(CZ * h + CS * s - CT * v + bv[n], 0.f);
                    }
                    Out[base + col] = f2b(v);
                }
            }
        }
    }
}

// Gram partials: P[b][128][128] = sum over this block's 64-row chunks of Hb^T Hb
__global__ __launch_bounds__(256)
void gram_mfma(const u16* __restrict__ Hb, float* __restrict__ P, int nrows)
{
    __shared__ __align__(16) u16 ht[2][128 * GCH];  // ht[c*GCH + (k ^ ((c&7)<<3))]
    const int t = threadIdx.x;
    const int w = t >> 6, l = t & 63;
    const int l15 = l & 15, g = l >> 4;
    const int nch = (nrows + GCH - 1) / GCH;

    f32x4 acc[2][8] = {};

    const int sr = t >> 2, sq = t & 3;   // staging: row sr, col-quarter sq

    // prologue stage
    {
        int gr = blockIdx.x * GCH + sr;
        #pragma unroll
        for (int i4 = 0; i4 < 4; ++i4) {
            int c0 = sq * 32 + i4 * 8;
            s16x8 v = {};
            if (gr < nrows) v = *(const s16x8*)&Hb[(size_t)gr * DH + c0];
            #pragma unroll
            for (int i = 0; i < 8; ++i) {
                int c = c0 + i;
                ht[0][c * GCH + (sr ^ ((c & 7) << 3))] = (u16)v[i];
            }
        }
    }
    __syncthreads();

    int buf = 0;
    for (int ch = blockIdx.x; ch < nch; ch += gridDim.x, buf ^= 1) {
        int chn = ch + gridDim.x;
        if (chn < nch) {   // stage next into other buffer
            int gr = chn * GCH + sr;
            #pragma unroll
            for (int i4 = 0; i4 < 4; ++i4) {
                int c0 = sq * 32 + i4 * 8;
                s16x8 v = {};
                if (gr < nrows) v = *(const s16x8*)&Hb[(size_t)gr * DH + c0];
                #pragma unroll
                for (int i = 0; i < 8; ++i) {
                    int c = c0 + i;
                    ht[buf ^ 1][c * GCH + (sr ^ ((c & 7) << 3))] = (u16)v[i];
                }
            }
        }
        #pragma unroll
        for (int ks = 0; ks < 2; ++ks) {
            const int kx = (ks * 32 + g * 8) ^ ((l & 7) << 3);
            s16x8 a0 = *(const s16x8*)&ht[buf][(w * 32 +      l15) * GCH + kx];
            s16x8 a1 = *(const s16x8*)&ht[buf][(w * 32 + 16 + l15) * GCH + kx];
            #pragma unroll
            for (int n = 0; n < 8; ++n) {
                s16x8 bfr = *(const s16x8*)&ht[buf][(n * 16 + l15) * GCH + kx];
                acc[0][n] = __builtin_amdgcn_mfma_f32_16x16x32_bf16(a0, bfr, acc[0][n], 0, 0, 0);
                acc[1][n] = __builtin_amdgcn_mfma_f32_16x16x32_bf16(a1, bfr, acc[1][n], 0, 0, 0);
            }
        }
        __syncthreads();
    }

    float* Pb = P + (size_t)blockIdx.x * (DH * DH);
    #pragma unroll
    for (int m = 0; m < 2; ++m)
        #pragma unroll
        for (int j = 0; j < 4; ++j) {
            int prow = w * 32 + m * 16 + g * 4 + j;
            #pragma unroll
            for (int n = 0; n < 8; ++n)
                Pb[prow * DH + n * 16 + l15] = acc[m][n][j];
        }
}

// deterministic reduce of partials -> G bf16 (G is symmetric: no transpose needed)
__global__ __launch_bounds__(256)
void gram_reduce(const float* __restrict__ P, u16* __restrict__ Gb) {
    int idx = blockIdx.x * 256 + threadIdx.x;   // grid 64 -> 16384
    float s = 0.f;
    #pragma unroll 8
    for (int p = 0; p < GRAM_BLK; ++p)
        s += P[(size_t)p * (DH * DH) + idx];
    Gb[idx] = f2b(s);
}

// FC + log_softmax via MFMA: logits = Xb @ Wf + bf, then in-register softmax.
__global__ __launch_bounds__(256)
void fc_mfma(const u16* __restrict__ Xb, const float* __restrict__ Wf,
             const float* __restrict__ bf, float* __restrict__ out, int nrows)
{
    __shared__ __align__(16) u16 wt[KCLS * DH];   // wt[c*128 + (k ^ ((c&7)<<3))]
    const int t = threadIdx.x;
    const int w = t >> 6, l = t & 63;
    const int l15 = l & 15, g = l >> 4;
    const int row0 = blockIdx.x * 128 + w * 32;

    for (int idx = t; idx < KCLS * DH; idx += 256) {
        int c = idx >> 7, k = idx & 127;
        wt[c * DH + (k ^ ((c & 7) << 3))] = f2b(Wf[k * KCLS + c]);
    }
    __syncthreads();

    int r[2];
    r[0] = min(row0 + l15,      nrows - 1);
    r[1] = min(row0 + 16 + l15, nrows - 1);

    f32x4 acc[2] = {};
    #pragma unroll
    for (int k0 = 0; k0 < DH; k0 += 32) {
        s16x8 a0 = *(const s16x8*)&Xb[(size_t)r[0] * DH + k0 + g * 8];
        s16x8 a1 = *(const s16x8*)&Xb[(size_t)r[1] * DH + k0 + g * 8];
        s16x8 bfr = *(const s16x8*)&wt[l15 * DH + ((k0 + g * 8) ^ ((l & 7) << 3))];
        acc[0] = __builtin_amdgcn_mfma_f32_16x16x32_bf16(a0, bfr, acc[0], 0, 0, 0);
        acc[1] = __builtin_amdgcn_mfma_f32_16x16x32_bf16(a1, bfr, acc[1], 0, 0, 0);
    }

    const float bias = bf[l15];
    #pragma unroll
    for (int m = 0; m < 2; ++m) {
        #pragma unroll
        for (int j = 0; j < 4; ++j) {
            int grow = row0 + m * 16 + g * 4 + j;
            float v = acc[m][j] + bias;
            float mx = v;
            #pragma unroll
            for (int o = 8; o >= 1; o >>= 1)
                mx = fmaxf(mx, __shfl_xor(mx, o));
            float e = expf(v - mx);
            float ssum = e;
            #pragma unroll
            for (int o = 8; o >= 1; o >>= 1)
                ssum += __shfl_xor(ssum, o);
            if (grow < nrows)
                out[(size_t)grow * KCLS + l15] = v - mx - logf(ssum);
        }
    }
}

extern "C" void kernel_launch(void* const* d_in, const int* in_sizes, int n_in,
                              void* d_out, int out_size, void* d_ws, size_t ws_size,
                              hipStream_t stream) {
    const float* x  = (const float*)d_in[0];
    const int*   ei = (const int*)d_in[1];
    const float* W1 = (const float*)d_in[2];
    const float* b1 = (const float*)d_in[3];
    const float* W2 = (const float*)d_in[4];
    const float* b2 = (const float*)d_in[5];
    const float* Wf = (const float*)d_in[6];
    const float* bf = (const float*)d_in[7];
    float* out = (float*)d_out;

    const int* row = ei;            // edge_index[0] = source
    const int* col = ei + NEDGES;   // edge_index[1] = target

    float* dinv    = (float*)d_ws;                       // 102400 f
    float* P       = dinv + 102400;                      // 256*16384 f
    int*   counts  = (int*)(P + (size_t)GRAM_BLK * DH * DH);  // 102400
    int*   offsets = counts + 102400;                    // 102656
    int*   bsum    = offsets + 102656;                   // 128
    int*   eidx    = bsum + 128;                         // E
    float* ew      = (float*)(eidx + NEDGES);            // E
    u16*   B0b     = (u16*)(ew + NEDGES);                // N*128
    u16*   xb      = B0b + (size_t)NNODES * DH;          // N*256 (dead after mm1)
    u16*   B1b     = xb;                                 // alias: xb low half
    u16*   Sb      = xb + (size_t)NNODES * DH;           // alias: xb high half
    u16*   W1t     = xb + (size_t)NNODES * DIN;          // 128*256
    u16*   W2t     = W1t + 128 * DIN;                    // 128*128
    u16*   Gb      = W2t + 128 * DH;                     // 128*128

    dim3 b256(256);
    const int gN  = (NNODES + 255) / 256;
    const int gE  = (NEDGES + 255) / 256;
    const int gMM = (NNODES + 127) / 128;         // 782
    const int gGA = (NNODES * 64 + 255) / 256;    // gather: 1 wave/node

    // ---- degrees + CSR build + input prep ----
    hipMemsetAsync(counts, 0, NNODES * sizeof(int), stream);
    hist_kernel<<<gE, b256, 0, stream>>>(col, counts);
    dinv_kernel<<<gN, b256, 0, stream>>>(counts, dinv);
    scan1_kernel<<<SCAN_NBLK, b256, 0, stream>>>(counts, offsets, bsum);
    scan2_kernel<<<1, 64, 0, stream>>>(bsum);
    scan3_kernel<<<SCAN_NBLK, b256, 0, stream>>>(offsets, bsum);
    hipMemsetAsync(counts, 0, NNODES * sizeof(int), stream);   // reuse as cursor
    fill_kernel<<<gE, b256, 0, stream>>>(row, col, dinv, offsets, counts, eidx, ew);
    cvt_x_kernel<<<2048, b256, 0, stream>>>(x, xb);
    tr_w_kernel<DIN><<<(128 * DIN + 255) / 256, b256, 0, stream>>>(W1, W1t);
    tr_w_kernel<DH><<<(128 * DH + 255) / 256, b256, 0, stream>>>(W2, W2t);

    // ---- layer 1 ----
    mm_bt<DIN, 0><<<gMM, b256, 0, stream>>>(xb, W1t, B0b, nullptr, nullptr, nullptr, NNODES);
    gram_mfma<<<GRAM_BLK, b256, 0, stream>>>(B0b, P, NNODES);
    gram_reduce<<<64, b256, 0, stream>>>(P, Gb);
    gather_b<<<gGA, b256, 0, stream>>>(B0b, dinv, offsets, eidx, ew, Sb);
    mm_bt<DH, 1><<<gMM, b256, 0, stream>>>(B0b, Gb, B1b, B0b, Sb, b1, NNODES);

    // ---- layer 2 ----
    mm_bt<DH, 0><<<gMM, b256, 0, stream>>>(B1b, W2t, B0b, nullptr, nullptr, nullptr, NNODES);
    gram_mfma<<<GRAM_BLK, b256, 0, stream>>>(B0b, P, NNODES);
    gram_reduce<<<64, b256, 0, stream>>>(P, Gb);
    gather_b<<<gGA, b256, 0, stream>>>(B0b, dinv, offsets, eidx, ew, Sb);
    mm_bt<DH, 1><<<gMM, b256, 0, stream>>>(B0b, Gb, B1b, B0b, Sb, b2, NNODES);

    // ---- fc + log_softmax (MFMA) ----
    fc_mfma<<<gMM, b256, 0, stream>>>(B1b, Wf, bf, out, NNODES);
}

// Round 7
// 332.234 us; speedup vs baseline: 4.9043x; 1.2710x over previous
//
#include <hip/hip_runtime.h>

#define NNODES 100000
#define NEDGES 800000
#define DIN    256
#define DH     128
#define KCLS   16
#define SCAN_NBLK 98   // ceil(100000/1024)
#define GCH 64         // gram K-chunk rows
#define GRAM_BLK 256   // gram partial blocks

typedef unsigned short u16;
typedef short s16x8 __attribute__((ext_vector_type(8)));
typedef float f32x4 __attribute__((ext_vector_type(4)));

static constexpr float CZ = 0.95f;   // 1 - gamma*l1 + gamma*l2
static constexpr float CS = 0.10f;   // gamma*l1
static constexpr float CT = 0.05f;   // gamma*l2

__device__ __forceinline__ u16 f2b(float f) {           // fp32 -> bf16 RNE
    unsigned u = __builtin_bit_cast(unsigned, f);
    return (u16)((u + 0x7FFFu + ((u >> 16) & 1u)) >> 16);
}
__device__ __forceinline__ float b2f(u16 b) {
    return __builtin_bit_cast(float, ((unsigned)b) << 16);
}

// ---------------- degree / CSR build ----------------

__global__ __launch_bounds__(256) void hist_kernel(const int* __restrict__ col, int* counts) {
    int i = blockIdx.x * 256 + threadIdx.x;
    if (i < NEDGES) atomicAdd(&counts[col[i]], 1);
}

__global__ __launch_bounds__(256) void dinv_kernel(const int* __restrict__ counts, float* dinv) {
    int i = blockIdx.x * 256 + threadIdx.x;
    if (i < NNODES) dinv[i] = rsqrtf((float)(counts[i] + 1));   // +1 self loop
}

__global__ __launch_bounds__(256) void scan1_kernel(const int* __restrict__ counts,
                                                    int* __restrict__ offsets, int* __restrict__ bsum) {
    __shared__ int ls[256];
    const int b = blockIdx.x, t = threadIdx.x;
    const int base = b * 1024 + t * 4;
    int v0 = (base + 0 < NNODES) ? counts[base + 0] : 0;
    int v1 = (base + 1 < NNODES) ? counts[base + 1] : 0;
    int v2 = (base + 2 < NNODES) ? counts[base + 2] : 0;
    int v3 = (base + 3 < NNODES) ? counts[base + 3] : 0;
    ls[t] = v0 + v1 + v2 + v3;
    __syncthreads();
    for (int off = 1; off < 256; off <<= 1) {
        int v = (t >= off) ? ls[t - off] : 0;
        __syncthreads();
        ls[t] += v;
        __syncthreads();
    }
    int excl = (t == 0) ? 0 : ls[t - 1];
    if (t == 255) bsum[b] = ls[255];
    if (base + 0 < NNODES) offsets[base + 0] = excl;
    if (base + 1 < NNODES) offsets[base + 1] = excl + v0;
    if (base + 2 < NNODES) offsets[base + 2] = excl + v0 + v1;
    if (base + 3 < NNODES) offsets[base + 3] = excl + v0 + v1 + v2;
}

__global__ void scan2_kernel(int* bsum) {
    if (threadIdx.x == 0 && blockIdx.x == 0) {
        int s = 0;
        for (int b = 0; b < SCAN_NBLK; ++b) { int v = bsum[b]; bsum[b] = s; s += v; }
    }
}

__global__ __launch_bounds__(256) void scan3_kernel(int* __restrict__ offsets, const int* __restrict__ bsum) {
    const int b = blockIdx.x, t = threadIdx.x;
    const int add = bsum[b];
    const int base = b * 1024 + t * 4;
    #pragma unroll
    for (int i = 0; i < 4; ++i)
        if (base + i < NNODES) offsets[base + i] += add;
    if (b == 0 && t == 0) offsets[NNODES] = NEDGES;
}

__global__ __launch_bounds__(256)
void fill_kernel(const int* __restrict__ row, const int* __restrict__ col,
                 const float* __restrict__ dinv, const int* __restrict__ offsets,
                 int* __restrict__ cursor, int* __restrict__ eidx, float* __restrict__ ew) {
    int e = blockIdx.x * 256 + threadIdx.x;
    if (e >= NEDGES) return;
    int c = col[e], r = row[e];
    int p = offsets[c] + atomicAdd(&cursor[c], 1);
    eidx[p] = r;
    ew[p] = dinv[r] * dinv[c];
}

// S[c] = dinv[c]^2 * H[c] + sum_{e->c} w_e * H[row_e]
// 16-lane group per node (16 B/lane), 4 nodes/wave, edge loop unrolled x2
// -> ~8 outstanding 256B row reads per wave.
__global__ __launch_bounds__(256)
void gather_b(const u16* __restrict__ Hb, const float* __restrict__ dinv,
              const int* __restrict__ offsets, const int* __restrict__ eidx,
              const float* __restrict__ ew, u16* __restrict__ Sb) {
    const int t = threadIdx.x;
    const int grp = t >> 4;           // 16 groups per block
    const int gl  = t & 15;           // lane within group
    const int node = blockIdx.x * 16 + grp;
    if (node >= NNODES) return;
    const s16x8* H8 = (const s16x8*)Hb;   // 16 s16x8 per row
    float d = dinv[node];
    s16x8 hv = H8[(size_t)node * 16 + gl];
    float a[8];
    #pragma unroll
    for (int i = 0; i < 8; ++i) a[i] = d * d * b2f((u16)hv[i]);
    int p = offsets[node];
    const int e = offsets[node + 1];
    for (; p + 1 < e; p += 2) {
        int   r0 = eidx[p],  r1 = eidx[p + 1];
        float w0 = ew[p],    w1 = ew[p + 1];
        s16x8 h0 = H8[(size_t)r0 * 16 + gl];
        s16x8 h1 = H8[(size_t)r1 * 16 + gl];
        #pragma unroll
        for (int i = 0; i < 8; ++i) a[i] = fmaf(w0, b2f((u16)h0[i]), a[i]);
        #pragma unroll
        for (int i = 0; i < 8; ++i) a[i] = fmaf(w1, b2f((u16)h1[i]), a[i]);
    }
    if (p < e) {
        int   r0 = eidx[p];
        float w0 = ew[p];
        s16x8 h0 = H8[(size_t)r0 * 16 + gl];
        #pragma unroll
        for (int i = 0; i < 8; ++i) a[i] = fmaf(w0, b2f((u16)h0[i]), a[i]);
    }
    s16x8 o;
    #pragma unroll
    for (int i = 0; i < 8; ++i) o[i] = (short)f2b(a[i]);
    ((s16x8*)Sb)[(size_t)node * 16 + gl] = o;
}

// ---------------- prep kernels ----------------

// x fp32 -> bf16, vectorized (float4 x2 -> s16x8)
__global__ __launch_bounds__(256)
void cvt_x_kernel(const float* __restrict__ x, u16* __restrict__ xb) {
    const long total = (long)NNODES * DIN / 8;
    for (long i = blockIdx.x * 256L + threadIdx.x; i < total; i += (long)gridDim.x * 256) {
        const float4* p = (const float4*)&x[i * 8];
        float4 u0 = p[0], u1 = p[1];
        s16x8 v;
        v[0] = (short)f2b(u0.x); v[1] = (short)f2b(u0.y);
        v[2] = (short)f2b(u0.z); v[3] = (short)f2b(u0.w);
        v[4] = (short)f2b(u1.x); v[5] = (short)f2b(u1.y);
        v[6] = (short)f2b(u1.z); v[7] = (short)f2b(u1.w);
        *(s16x8*)&xb[i * 8] = v;
    }
}

// W fp32 [KD][128] -> Wt bf16 [128][KD]
template<int KD>
__global__ __launch_bounds__(256)
void tr_w_kernel(const float* __restrict__ W, u16* __restrict__ Wt) {
    int idx = blockIdx.x * 256 + threadIdx.x;
    if (idx < 128 * KD) {
        int c = idx / KD, k = idx % KD;
        Wt[idx] = f2b(W[k * 128 + c]);
    }
}

// ---------------- MFMA dense kernels ----------------
// Out[N x 128] = A[N x KD] @ B[KD x 128], A bf16 row-major, Bt bf16 [c][k].
// Per-32k-chunk double-buffered LDS tiles (padded stride 40), b128 everywhere.
// EPI=1: Bt is G; Out = relu(CZ*Hb + CS*Sb - CT*(A@G) + bias).
template<int KD, int EPI>
__global__ __launch_bounds__(256, 4)
void mm_bt(const u16* __restrict__ A, const u16* __restrict__ Bt,
           u16* __restrict__ Out, const u16* __restrict__ Hb,
           const u16* __restrict__ Sb, const float* __restrict__ bias,
           int nrows)
{
    __shared__ __align__(16) u16 as_[2][128 * 40];
    __shared__ __align__(16) u16 bs_[2][128 * 40];
    const int t = threadIdx.x;
    const int w = t >> 6, l = t & 63;
    const int l15 = l & 15, g = l >> 4;
    const int row0 = blockIdx.x * 128;

    const int sr = t >> 2, so = t & 3;   // staging: row (0..63), k-octet (0..3)
    int arow[2];
    arow[0] = min(row0 + sr,      nrows - 1);
    arow[1] = min(row0 + 64 + sr, nrows - 1);

    // prologue: stage chunk 0 into buf 0
    #pragma unroll
    for (int i = 0; i < 2; ++i) {
        s16x8 va = *(const s16x8*)&A [(size_t)arow[i] * KD + so * 8];
        s16x8 vb = *(const s16x8*)&Bt[(size_t)(sr + i * 64) * KD + so * 8];
        *(s16x8*)&as_[0][(sr + i * 64) * 40 + so * 8] = va;
        *(s16x8*)&bs_[0][(sr + i * 64) * 40 + so * 8] = vb;
    }
    __syncthreads();

    f32x4 acc[2][8] = {};
    constexpr int NK = KD / 32;

    for (int kc = 0; kc < NK; ++kc) {
        const int buf = kc & 1;
        // issue next chunk's global loads early (hide under MFMA)
        s16x8 va[2], vb[2];
        const bool pf = (kc + 1 < NK);
        if (pf) {
            const int k0 = (kc + 1) * 32;
            #pragma unroll
            for (int i = 0; i < 2; ++i) {
                va[i] = *(const s16x8*)&A [(size_t)arow[i] * KD + k0 + so * 8];
                vb[i] = *(const s16x8*)&Bt[(size_t)(sr + i * 64) * KD + k0 + so * 8];
            }
        }
        // compute current chunk
        s16x8 af0 = *(const s16x8*)&as_[buf][(w * 32 +      l15) * 40 + g * 8];
        s16x8 af1 = *(const s16x8*)&as_[buf][(w * 32 + 16 + l15) * 40 + g * 8];
        #pragma unroll
        for (int n = 0; n < 8; ++n) {
            s16x8 bfr = *(const s16x8*)&bs_[buf][(n * 16 + l15) * 40 + g * 8];
            acc[0][n] = __builtin_amdgcn_mfma_f32_16x16x32_bf16(af0, bfr, acc[0][n], 0, 0, 0);
            acc[1][n] = __builtin_amdgcn_mfma_f32_16x16x32_bf16(af1, bfr, acc[1][n], 0, 0, 0);
        }
        // write next chunk into the other buffer
        if (pf) {
            #pragma unroll
            for (int i = 0; i < 2; ++i) {
                *(s16x8*)&as_[buf ^ 1][(sr + i * 64) * 40 + so * 8] = va[i];
                *(s16x8*)&bs_[buf ^ 1][(sr + i * 64) * 40 + so * 8] = vb[i];
            }
        }
        __syncthreads();
    }

    float bv[8];
    if (EPI) {
        #pragma unroll
        for (int n = 0; n < 8; ++n) bv[n] = bias[n * 16 + l15];
    }
    #pragma unroll
    for (int m = 0; m < 2; ++m) {
        #pragma unroll
        for (int j = 0; j < 4; ++j) {
            int grow = row0 + w * 32 + m * 16 + g * 4 + j;
            if (grow < nrows) {
                size_t base = (size_t)grow * 128;
                #pragma unroll
                for (int n = 0; n < 8; ++n) {
                    int col = n * 16 + l15;
                    float v = acc[m][n][j];
                    if (EPI) {
                        float h = b2f(Hb[base + col]);
                        float s = b2f(Sb[base + col]);
                        v = fmaxf(CZ * h + CS * s - CT * v + bv[n], 0.f);
                    }
                    Out[base + col] = f2b(v);
                }
            }
        }
    }
}

// Gram partials: P[b][128][128] = sum over this block's 64-row chunks of Hb^T Hb
__global__ __launch_bounds__(256)
void gram_mfma(const u16* __restrict__ Hb, float* __restrict__ P, int nrows)
{
    __shared__ __align__(16) u16 ht[2][128 * GCH];  // ht[c*GCH + (k ^ ((c&7)<<3))]
    const int t = threadIdx.x;
    const int w = t >> 6, l = t & 63;
    const int l15 = l & 15, g = l >> 4;
    const int nch = (nrows + GCH - 1) / GCH;

    f32x4 acc[2][8] = {};

    const int sr = t >> 2, sq = t & 3;   // staging: row sr, col-quarter sq

    // prologue stage
    {
        int gr = blockIdx.x * GCH + sr;
        #pragma unroll
        for (int i4 = 0; i4 < 4; ++i4) {
            int c0 = sq * 32 + i4 * 8;
            s16x8 v = {};
            if (gr < nrows) v = *(const s16x8*)&Hb[(size_t)gr * DH + c0];
            #pragma unroll
            for (int i = 0; i < 8; ++i) {
                int c = c0 + i;
                ht[0][c * GCH + (sr ^ ((c & 7) << 3))] = (u16)v[i];
            }
        }
    }
    __syncthreads();

    int buf = 0;
    for (int ch = blockIdx.x; ch < nch; ch += gridDim.x, buf ^= 1) {
        int chn = ch + gridDim.x;
        if (chn < nch) {   // stage next into other buffer
            int gr = chn * GCH + sr;
            #pragma unroll
            for (int i4 = 0; i4 < 4; ++i4) {
                int c0 = sq * 32 + i4 * 8;
                s16x8 v = {};
                if (gr < nrows) v = *(const s16x8*)&Hb[(size_t)gr * DH + c0];
                #pragma unroll
                for (int i = 0; i < 8; ++i) {
                    int c = c0 + i;
                    ht[buf ^ 1][c * GCH + (sr ^ ((c & 7) << 3))] = (u16)v[i];
                }
            }
        }
        #pragma unroll
        for (int ks = 0; ks < 2; ++ks) {
            const int kx = (ks * 32 + g * 8) ^ ((l & 7) << 3);
            s16x8 a0 = *(const s16x8*)&ht[buf][(w * 32 +      l15) * GCH + kx];
            s16x8 a1 = *(const s16x8*)&ht[buf][(w * 32 + 16 + l15) * GCH + kx];
            #pragma unroll
            for (int n = 0; n < 8; ++n) {
                s16x8 bfr = *(const s16x8*)&ht[buf][(n * 16 + l15) * GCH + kx];
                acc[0][n] = __builtin_amdgcn_mfma_f32_16x16x32_bf16(a0, bfr, acc[0][n], 0, 0, 0);
                acc[1][n] = __builtin_amdgcn_mfma_f32_16x16x32_bf16(a1, bfr, acc[1][n], 0, 0, 0);
            }
        }
        __syncthreads();
    }

    float* Pb = P + (size_t)blockIdx.x * (DH * DH);
    #pragma unroll
    for (int m = 0; m < 2; ++m)
        #pragma unroll
        for (int j = 0; j < 4; ++j) {
            int prow = w * 32 + m * 16 + g * 4 + j;
            #pragma unroll
            for (int n = 0; n < 8; ++n)
                Pb[prow * DH + n * 16 + l15] = acc[m][n][j];
        }
}

// deterministic reduce of partials -> G bf16 (G is symmetric: no transpose needed)
__global__ __launch_bounds__(256)
void gram_reduce(const float* __restrict__ P, u16* __restrict__ Gb) {
    int idx = blockIdx.x * 256 + threadIdx.x;   // grid 64 -> 16384
    float s = 0.f;
    #pragma unroll 8
    for (int p = 0; p < GRAM_BLK; ++p)
        s += P[(size_t)p * (DH * DH) + idx];
    Gb[idx] = f2b(s);
}

// FC + log_softmax via MFMA: logits = Xb @ Wf + bf, then in-register softmax.
__global__ __launch_bounds__(256)
void fc_mfma(const u16* __restrict__ Xb, const float* __restrict__ Wf,
             const float* __restrict__ bf, float* __restrict__ out, int nrows)
{
    __shared__ __align__(16) u16 wt[KCLS * DH];   // wt[c*128 + (k ^ ((c&7)<<3))]
    const int t = threadIdx.x;
    const int w = t >> 6, l = t & 63;
    const int l15 = l & 15, g = l >> 4;
    const int row0 = blockIdx.x * 128 + w * 32;

    for (int idx = t; idx < KCLS * DH; idx += 256) {
        int c = idx >> 7, k = idx & 127;
        wt[c * DH + (k ^ ((c & 7) << 3))] = f2b(Wf[k * KCLS + c]);
    }
    __syncthreads();

    int r[2];
    r[0] = min(row0 + l15,      nrows - 1);
    r[1] = min(row0 + 16 + l15, nrows - 1);

    f32x4 acc[2] = {};
    #pragma unroll
    for (int k0 = 0; k0 < DH; k0 += 32) {
        s16x8 a0 = *(const s16x8*)&Xb[(size_t)r[0] * DH + k0 + g * 8];
        s16x8 a1 = *(const s16x8*)&Xb[(size_t)r[1] * DH + k0 + g * 8];
        s16x8 bfr = *(const s16x8*)&wt[l15 * DH + ((k0 + g * 8) ^ ((l & 7) << 3))];
        acc[0] = __builtin_amdgcn_mfma_f32_16x16x32_bf16(a0, bfr, acc[0], 0, 0, 0);
        acc[1] = __builtin_amdgcn_mfma_f32_16x16x32_bf16(a1, bfr, acc[1], 0, 0, 0);
    }

    const float bias = bf[l15];
    #pragma unroll
    for (int m = 0; m < 2; ++m) {
        #pragma unroll
        for (int j = 0; j < 4; ++j) {
            int grow = row0 + m * 16 + g * 4 + j;
            float v = acc[m][j] + bias;
            float mx = v;
            #pragma unroll
            for (int o = 8; o >= 1; o >>= 1)
                mx = fmaxf(mx, __shfl_xor(mx, o));
            float e = expf(v - mx);
            float ssum = e;
            #pragma unroll
            for (int o = 8; o >= 1; o >>= 1)
                ssum += __shfl_xor(ssum, o);
            if (grow < nrows)
                out[(size_t)grow * KCLS + l15] = v - mx - logf(ssum);
        }
    }
}

extern "C" void kernel_launch(void* const* d_in, const int* in_sizes, int n_in,
                              void* d_out, int out_size, void* d_ws, size_t ws_size,
                              hipStream_t stream) {
    const float* x  = (const float*)d_in[0];
    const int*   ei = (const int*)d_in[1];
    const float* W1 = (const float*)d_in[2];
    const float* b1 = (const float*)d_in[3];
    const float* W2 = (const float*)d_in[4];
    const float* b2 = (const float*)d_in[5];
    const float* Wf = (const float*)d_in[6];
    const float* bf = (const float*)d_in[7];
    float* out = (float*)d_out;

    const int* row = ei;            // edge_index[0] = source
    const int* col = ei + NEDGES;   // edge_index[1] = target

    float* dinv    = (float*)d_ws;                       // 102400 f
    float* P       = dinv + 102400;                      // 256*16384 f
    int*   counts  = (int*)(P + (size_t)GRAM_BLK * DH * DH);  // 102400
    int*   offsets = counts + 102400;                    // 102656
    int*   bsum    = offsets + 102656;                   // 128
    int*   eidx    = bsum + 128;                         // E
    float* ew      = (float*)(eidx + NEDGES);            // E
    u16*   B0b     = (u16*)(ew + NEDGES);                // N*128
    u16*   xb      = B0b + (size_t)NNODES * DH;          // N*256 (dead after mm1)
    u16*   B1b     = xb;                                 // alias: xb low half
    u16*   Sb      = xb + (size_t)NNODES * DH;           // alias: xb high half
    u16*   W1t     = xb + (size_t)NNODES * DIN;          // 128*256
    u16*   W2t     = W1t + 128 * DIN;                    // 128*128
    u16*   Gb      = W2t + 128 * DH;                     // 128*128

    dim3 b256(256);
    const int gN  = (NNODES + 255) / 256;
    const int gE  = (NEDGES + 255) / 256;
    const int gMM = (NNODES + 127) / 128;         // 782
    const int gGA = (NNODES + 15) / 16;           // gather: 16 nodes/block

    // ---- degrees + CSR build + input prep ----
    hipMemsetAsync(counts, 0, NNODES * sizeof(int), stream);
    hist_kernel<<<gE, b256, 0, stream>>>(col, counts);
    dinv_kernel<<<gN, b256, 0, stream>>>(counts, dinv);
    scan1_kernel<<<SCAN_NBLK, b256, 0, stream>>>(counts, offsets, bsum);
    scan2_kernel<<<1, 64, 0, stream>>>(bsum);
    scan3_kernel<<<SCAN_NBLK, b256, 0, stream>>>(offsets, bsum);
    hipMemsetAsync(counts, 0, NNODES * sizeof(int), stream);   // reuse as cursor
    fill_kernel<<<gE, b256, 0, stream>>>(row, col, dinv, offsets, counts, eidx, ew);
    cvt_x_kernel<<<2048, b256, 0, stream>>>(x, xb);
    tr_w_kernel<DIN><<<(128 * DIN + 255) / 256, b256, 0, stream>>>(W1, W1t);
    tr_w_kernel<DH><<<(128 * DH + 255) / 256, b256, 0, stream>>>(W2, W2t);

    // ---- layer 1 ----
    mm_bt<DIN, 0><<<gMM, b256, 0, stream>>>(xb, W1t, B0b, nullptr, nullptr, nullptr, NNODES);
    gram_mfma<<<GRAM_BLK, b256, 0, stream>>>(B0b, P, NNODES);
    gram_reduce<<<64, b256, 0, stream>>>(P, Gb);
    gather_b<<<gGA, b256, 0, stream>>>(B0b, dinv, offsets, eidx, ew, Sb);
    mm_bt<DH, 1><<<gMM, b256, 0, stream>>>(B0b, Gb, B1b, B0b, Sb, b1, NNODES);

    // ---- layer 2 ----
    mm_bt<DH, 0><<<gMM, b256, 0, stream>>>(B1b, W2t, B0b, nullptr, nullptr, nullptr, NNODES);
    gram_mfma<<<GRAM_BLK, b256, 0, stream>>>(B0b, P, NNODES);
    gram_reduce<<<64, b256, 0, stream>>>(P, Gb);
    gather_b<<<gGA, b256, 0, stream>>>(B0b, dinv, offsets, eidx, ew, Sb);
    mm_bt<DH, 1><<<gMM, b256, 0, stream>>>(B0b, Gb, B1b, B0b, Sb, b2, NNODES);

    // ---- fc + log_softmax (MFMA) ----
    fc_mfma<<<gMM, b256, 0, stream>>>(B1b, Wf, bf, out, NNODES);
}